// Round 5
// baseline (1267.038 us; speedup 1.0000x reference)
//
#include <hip/hip_runtime.h>
#include <hip/hip_cooperative_groups.h>

namespace cg = cooperative_groups;

#define BN_EPS 1e-5f

typedef __bf16 bf16x8 __attribute__((ext_vector_type(8)));
typedef float f32x4 __attribute__((ext_vector_type(4)));
typedef unsigned int uint;
typedef unsigned short ushort;

__device__ __forceinline__ ushort f2bf(float f) {
  union { float f; uint u; } v; v.f = f;
  uint r = v.u + 0x7FFF + ((v.u >> 16) & 1);   // RNE
  return (ushort)(r >> 16);
}
__device__ __forceinline__ float bf2f_lo(uint u) {
  union { uint i; float f; } v; v.i = u << 16; return v.f;
}
__device__ __forceinline__ float bf2f_hi(uint u) {
  union { uint i; float f; } v; v.i = u & 0xffff0000u; return v.f;
}
__device__ __forceinline__ uint pack2(float a, float b) {
  return (uint)f2bf(a) | ((uint)f2bf(b) << 16);
}

struct Args {
  const float* x;
  const int* src;
  const int* dst;
  const float* W_in; const float* b_in;
  const float* bng_in; const float* bnb_in; const float* bnm_in; const float* bnv_in;
  const float* Wl; const float* bl; const float* Wr;
  const float* bng; const float* bnb; const float* bnm; const float* bnv;
  int* cnt; int* cur; int* cursor;
  int* rowbeg; int* col;
  ushort* Bfm; ushort* hA; ushort* hB; ushort* agg;
  float* out;
  int N, E, NB, EB, GB, NG;
};

// ---- gemm_in tile (identical math to the standalone round-4 kernel) ----
__device__ __forceinline__ void gemm_in_tile(const Args& a, int t, float* Cb_all) {
  int tid = threadIdx.x, wave = tid >> 6, lane = tid & 63;
  int wm = wave >> 1, wn = wave & 1, quad = lane >> 4, l16 = lane & 15;
  int m0 = t * 64;
  const float* X = a.x;
  int N = a.N;

  int rowm[2];
  #pragma unroll
  for (int mt = 0; mt < 2; ++mt) {
    int r = m0 + wm * 32 + mt * 16 + l16;
    rowm[mt] = r < N ? r : N - 1;
  }

  float4 f_buf[2][2][2];
  uint4 b_buf[2][4];
  #pragma unroll
  for (int mt = 0; mt < 2; ++mt) {
    const float* p = X + (size_t)rowm[mt] * 256 + quad * 8;
    f_buf[0][mt][0] = *(const float4*)p;
    f_buf[0][mt][1] = *(const float4*)(p + 4);
  }
  {
    const ushort* bp = a.Bfm + (size_t)(wn * 4 * 256 + lane) * 8;
    #pragma unroll
    for (int nt = 0; nt < 4; ++nt)
      b_buf[0][nt] = *(const uint4*)(bp + nt * 2048);
  }

  f32x4 acc[2][4] = {};

  #pragma unroll
  for (int kt = 0; kt < 8; ++kt) {
    if (kt < 7) {
      int k1 = kt + 1;
      int ko = k1 * 32 + quad * 8;
      #pragma unroll
      for (int mt = 0; mt < 2; ++mt) {
        const float* p = X + (size_t)rowm[mt] * 256 + ko;
        f_buf[k1 & 1][mt][0] = *(const float4*)p;
        f_buf[k1 & 1][mt][1] = *(const float4*)(p + 4);
      }
      const ushort* bp = a.Bfm + ((size_t)(k1 >> 2) * 16384 +
                                  (size_t)((wn * 4) * 256 + (k1 & 3) * 64 + lane) * 8);
      #pragma unroll
      for (int nt = 0; nt < 4; ++nt)
        b_buf[k1 & 1][nt] = *(const uint4*)(bp + nt * 2048);
    }
    __builtin_amdgcn_sched_barrier(0);
    #pragma unroll
    for (int mt = 0; mt < 2; ++mt) {
      float4 lo = f_buf[kt & 1][mt][0], hi = f_buf[kt & 1][mt][1];
      uint4 av;
      av.x = pack2(lo.x, lo.y); av.y = pack2(lo.z, lo.w);
      av.z = pack2(hi.x, hi.y); av.w = pack2(hi.z, hi.w);
      bf16x8 af = __builtin_bit_cast(bf16x8, av);
      #pragma unroll
      for (int nt = 0; nt < 4; ++nt)
        acc[mt][nt] = __builtin_amdgcn_mfma_f32_16x16x32_bf16(
            af, __builtin_bit_cast(bf16x8, b_buf[kt & 1][nt]), acc[mt][nt], 0, 0, 0);
    }
  }

  #pragma unroll
  for (int nt = 0; nt < 4; ++nt) {
    int c = wn * 64 + nt * 16 + l16;
    float sc = a.bng_in[c] * rsqrtf(a.bnv_in[c] + BN_EPS);
    float sh = a.bnb_in[c] - a.bnm_in[c] * sc;
    float bi = a.b_in[c];
    #pragma unroll
    for (int mt = 0; mt < 2; ++mt)
      #pragma unroll
      for (int r = 0; r < 4; ++r)
        acc[mt][nt][r] = fmaxf((acc[mt][nt][r] + bi) * sc + sh, 0.f);
  }

  float* Cb = Cb_all + wave * (16 * 68);
  #pragma unroll
  for (int mt = 0; mt < 2; ++mt) {
    #pragma unroll
    for (int nt = 0; nt < 4; ++nt)
      #pragma unroll
      for (int r = 0; r < 4; ++r)
        Cb[(quad * 4 + r) * 68 + nt * 16 + l16] = acc[mt][nt][r];
    #pragma unroll
    for (int i = 0; i < 4; ++i) {
      int idx = i * 64 + lane, rowl = idx >> 4, seg = idx & 15;
      int grow = m0 + wm * 32 + mt * 16 + rowl;
      if (grow < N) {
        float4 vv = *(float4*)&Cb[rowl * 68 + seg * 4];
        uint2 o;
        o.x = pack2(vv.x, vv.y); o.y = pack2(vv.z, vv.w);
        *(uint2*)(a.hA + (size_t)grow * 128 + wn * 64 + seg * 4) = o;
      }
    }
  }
}

// ---- gemm_layer tile (identical math to the standalone round-4 kernel) ----
__device__ __forceinline__ void gemm_layer_tile(const Args& a, int t, const ushort* h_in,
                                                const ushort* BfmL, const float* biasL,
                                                const float* gamma, const float* beta,
                                                const float* mean, const float* var,
                                                void* outp, bool f32out, float* Cb_all) {
  int tid = threadIdx.x, wave = tid >> 6, lane = tid & 63;
  int wm = wave >> 1, wn = wave & 1, quad = lane >> 4, l16 = lane & 15;
  int m0 = t * 64;
  int N = a.N;
  const ushort* A0 = a.agg;
  const ushort* A1 = h_in;

  int rowm[2];
  #pragma unroll
  for (int mt = 0; mt < 2; ++mt) {
    int r = m0 + wm * 32 + mt * 16 + l16;
    rowm[mt] = r < N ? r : N - 1;
  }

  uint4 a_buf[2][2], b_buf[2][4];
  #pragma unroll
  for (int mt = 0; mt < 2; ++mt)
    a_buf[0][mt] = *(const uint4*)(A0 + (size_t)rowm[mt] * 128 + quad * 8);
  {
    const ushort* bp = BfmL + (size_t)(wn * 4 * 256 + lane) * 8;
    #pragma unroll
    for (int nt = 0; nt < 4; ++nt)
      b_buf[0][nt] = *(const uint4*)(bp + nt * 2048);
  }

  f32x4 acc[2][4] = {};

  #pragma unroll
  for (int kt = 0; kt < 8; ++kt) {
    if (kt < 7) {
      int k1 = kt + 1;
      const ushort* bse = (k1 < 4) ? A0 : A1;
      int ko = (k1 & 3) * 32 + quad * 8;
      #pragma unroll
      for (int mt = 0; mt < 2; ++mt)
        a_buf[k1 & 1][mt] = *(const uint4*)(bse + (size_t)rowm[mt] * 128 + ko);
      const ushort* bp = BfmL + ((size_t)(k1 >> 2) * 16384 +
                                 (size_t)((wn * 4) * 256 + (k1 & 3) * 64 + lane) * 8);
      #pragma unroll
      for (int nt = 0; nt < 4; ++nt)
        b_buf[k1 & 1][nt] = *(const uint4*)(bp + nt * 2048);
    }
    __builtin_amdgcn_sched_barrier(0);
    #pragma unroll
    for (int mt = 0; mt < 2; ++mt) {
      bf16x8 af = __builtin_bit_cast(bf16x8, a_buf[kt & 1][mt]);
      #pragma unroll
      for (int nt = 0; nt < 4; ++nt)
        acc[mt][nt] = __builtin_amdgcn_mfma_f32_16x16x32_bf16(
            af, __builtin_bit_cast(bf16x8, b_buf[kt & 1][nt]), acc[mt][nt], 0, 0, 0);
    }
  }

  #pragma unroll
  for (int nt = 0; nt < 4; ++nt) {
    int c = wn * 64 + nt * 16 + l16;
    float sc = gamma[c] * rsqrtf(var[c] + BN_EPS);
    float sh = beta[c] - mean[c] * sc;
    float bi = biasL[c];
    #pragma unroll
    for (int mt = 0; mt < 2; ++mt)
      #pragma unroll
      for (int r = 0; r < 4; ++r)
        acc[mt][nt][r] = fmaxf((acc[mt][nt][r] + bi) * sc + sh, 0.f);
  }

  float* Cb = Cb_all + wave * (16 * 68);
  #pragma unroll
  for (int mt = 0; mt < 2; ++mt) {
    #pragma unroll
    for (int nt = 0; nt < 4; ++nt)
      #pragma unroll
      for (int r = 0; r < 4; ++r)
        Cb[(quad * 4 + r) * 68 + nt * 16 + l16] = acc[mt][nt][r];
    #pragma unroll
    for (int i = 0; i < 4; ++i) {
      int idx = i * 64 + lane, rowl = idx >> 4, seg = idx & 15;
      int grow = m0 + wm * 32 + mt * 16 + rowl;
      if (grow < N) {
        float4 vv = *(float4*)&Cb[rowl * 68 + seg * 4];
        uint2 rv = *(const uint2*)(h_in + (size_t)grow * 128 + wn * 64 + seg * 4);
        vv.x += bf2f_lo(rv.x); vv.y += bf2f_hi(rv.x);
        vv.z += bf2f_lo(rv.y); vv.w += bf2f_hi(rv.y);
        if (f32out) {
          *(float4*)((float*)outp + (size_t)grow * 128 + wn * 64 + seg * 4) = vv;
        } else {
          uint2 o;
          o.x = pack2(vv.x, vv.y); o.y = pack2(vv.z, vv.w);
          *(uint2*)((ushort*)outp + (size_t)grow * 128 + wn * 64 + seg * 4) = o;
        }
      }
    }
  }
}

// ---- mean aggregation for one 8-node group (half-wave per node) ----
__device__ __forceinline__ void agg_group(const Args& a, int g, const ushort* h_in) {
  int node = g * 8 + (threadIdx.x >> 5);
  if (node >= a.N) return;
  int lane = threadIdx.x & 31;
  const ushort* hp = h_in + lane * 4;
  int beg = a.rowbeg[node];
  int d = a.cnt[node];
  float di = 1.0f / (float)(d > 0 ? d : 1);
  float a0 = 0.f, a1 = 0.f, a2 = 0.f, a3 = 0.f;
  int e = beg, end = beg + d;
  const int* col = a.col;
  for (; e + 3 < end; e += 4) {
    uint2 v0 = *(const uint2*)(hp + (size_t)col[e] * 128);
    uint2 v1 = *(const uint2*)(hp + (size_t)col[e + 1] * 128);
    uint2 v2 = *(const uint2*)(hp + (size_t)col[e + 2] * 128);
    uint2 v3 = *(const uint2*)(hp + (size_t)col[e + 3] * 128);
    a0 += (bf2f_lo(v0.x) + bf2f_lo(v1.x)) + (bf2f_lo(v2.x) + bf2f_lo(v3.x));
    a1 += (bf2f_hi(v0.x) + bf2f_hi(v1.x)) + (bf2f_hi(v2.x) + bf2f_hi(v3.x));
    a2 += (bf2f_lo(v0.y) + bf2f_lo(v1.y)) + (bf2f_lo(v2.y) + bf2f_lo(v3.y));
    a3 += (bf2f_hi(v0.y) + bf2f_hi(v1.y)) + (bf2f_hi(v2.y) + bf2f_hi(v3.y));
  }
  for (; e < end; ++e) {
    uint2 v0 = *(const uint2*)(hp + (size_t)col[e] * 128);
    a0 += bf2f_lo(v0.x); a1 += bf2f_hi(v0.x);
    a2 += bf2f_lo(v0.y); a3 += bf2f_hi(v0.y);
  }
  uint2 o;
  o.x = pack2(a0 * di, a1 * di);
  o.y = pack2(a2 * di, a3 * di);
  *(uint2*)(a.agg + (size_t)node * 128 + lane * 4) = o;
}

// ---- the whole pipeline as one cooperative kernel, 10 phases / 9 grid syncs ----
// P0: zero cnt|cur|cursor + weight prep  -> P1: hist UNION gemm_in (independent,
// co-scheduled so the CSR histogram hides under the X stream) -> P2: CSR range
// reserve (wave-scan + atomic bump) -> P3: fill -> P4..: 3 x (agg, gemm_layer).
// All phase bodies are byte-identical math to the round-4 split kernels.
__global__ void mega(Args a) {
  __shared__ __align__(16) float Cb_all[4 * 16 * 68];
  cg::grid_group grid = cg::this_grid();
  const int tid = threadIdx.x;
  const int bid = blockIdx.x;
  const int nblk = gridDim.x;
  const int tstride = nblk * 256;
  const int t0 = bid * 256 + tid;

  // ---- P0: zero counters + weight prep (split-K fragment-major bf16) ----
  for (int i = t0; i < 2 * a.N + 1; i += tstride) a.cnt[i] = 0;   // cnt|cur|cursor contiguous
  for (int p = t0; p < 16384; p += tstride) {
    int mat = p >> 12;
    int rem = p & 4095;
    int half = rem >> 11;
    int rem2 = rem & 2047;
    int nt = rem2 >> 8, kt2 = (rem2 >> 6) & 3, lane = rem2 & 63;
    int n = nt * 16 + (lane & 15);
    int k0 = (half * 4 + kt2) * 32 + (lane >> 4) * 8;
    ushort tmp[8];
    #pragma unroll
    for (int j = 0; j < 8; ++j) {
      int k = k0 + j;
      float v;
      if (mat == 0) v = a.W_in[k * 128 + n];
      else {
        int l = mat - 1;
        v = (k < 128) ? a.Wl[l * 16384 + k * 128 + n]
                      : a.Wr[l * 16384 + (k - 128) * 128 + n];
      }
      tmp[j] = f2bf(v);
    }
    *(uint4*)&a.Bfm[(size_t)p * 8] = *(const uint4*)tmp;
  }
  grid.sync();

  // ---- P1: gemm_in tiles UNION hist chunks (independent work) ----
  for (int vb = bid; vb < a.GB + a.EB; vb += nblk) {
    if (vb < a.GB) {
      gemm_in_tile(a, vb, Cb_all);
    } else {
      int e = (vb - a.GB) * 256 + tid;
      if (e < a.E) atomicAdd(&a.cnt[a.dst[e]], 1);
    }
  }
  grid.sync();

  // ---- P2: reserve contiguous CSR ranges (wave-scan + single-cursor bump) ----
  for (int vb = bid; vb < a.NB; vb += nblk) {
    int i = vb * 256 + tid;
    int v = (i < a.N) ? a.cnt[i] : 0;
    int lane = tid & 63;
    int x = v;
    #pragma unroll
    for (int off = 1; off < 64; off <<= 1) {
      int y = __shfl_up(x, off, 64);
      if (lane >= off) x += y;
    }
    int ret = 0;
    if (lane == 63) ret = atomicAdd(a.cursor, x);
    int base = __shfl(ret, 63);
    if (i < a.N) a.rowbeg[i] = base + x - v;
  }
  grid.sync();

  // ---- P3: fill ----
  for (int e = t0; e < a.E; e += tstride) {
    int d = a.dst[e];
    int p = a.rowbeg[d] + atomicAdd(&a.cur[d], 1);
    a.col[p] = a.src[e];
  }
  grid.sync();

  // ---- P4..P9: 3 SAGE layers: (agg, gemm_layer) each ----
  #pragma unroll 1
  for (int l = 0; l < 3; ++l) {
    const ushort* h_in = (l & 1) ? a.hB : a.hA;
    for (int g = bid; g < a.NG; g += nblk) agg_group(a, g, h_in);
    grid.sync();
    const ushort* BfmL = a.Bfm + (size_t)(l + 1) * 32768;
    const float* biasL = a.bl + l * 128;
    void* outp = (l == 0) ? (void*)a.hB : (l == 1) ? (void*)a.hA : (void*)a.out;
    bool f32out = (l == 2);
    for (int t = bid; t < a.GB; t += nblk)
      gemm_layer_tile(a, t, h_in, BfmL, biasL,
                      a.bng + l * 128, a.bnb + l * 128, a.bnm + l * 128, a.bnv + l * 128,
                      outp, f32out, Cb_all);
    if (l < 2) grid.sync();
  }
}

// ---------------- launch ----------------

extern "C" void kernel_launch(void* const* d_in, const int* in_sizes, int n_in,
                              void* d_out, int out_size, void* d_ws, size_t ws_size,
                              hipStream_t stream) {
  const int N = in_sizes[0] / 256;
  const int E = in_sizes[1] / 2;

  char* ws = (char*)d_ws;
  size_t off = 0;
  auto alloc = [&](size_t bytes) {
    void* p = ws + off;
    off = (off + bytes + 255) & ~(size_t)255;
    return p;
  };
  int* zreg     = (int*)alloc((size_t)(2 * N + 1) * 4);   // cnt(deg) | cur | cursor
  int* rowbeg   = (int*)alloc((size_t)N * 4);
  int* col      = (int*)alloc((size_t)E * 4);
  ushort* Bfm   = (ushort*)alloc(4 * 32768 * 2);          // split-K frag-major: [in,l0,l1,l2]
  ushort* hA    = (ushort*)alloc((size_t)N * 128 * 2);
  ushort* hB    = (ushort*)alloc((size_t)N * 128 * 2);
  ushort* agg   = (ushort*)alloc((size_t)N * 128 * 2);
  (void)ws_size; (void)n_in; (void)out_size;

  Args a;
  a.x      = (const float*)d_in[0];
  a.src    = (const int*)d_in[1];
  a.dst    = (const int*)d_in[1] + E;
  a.W_in   = (const float*)d_in[2];
  a.b_in   = (const float*)d_in[3];
  a.bng_in = (const float*)d_in[4];
  a.bnb_in = (const float*)d_in[5];
  a.bnm_in = (const float*)d_in[6];
  a.bnv_in = (const float*)d_in[7];
  a.Wl     = (const float*)d_in[8];
  a.bl     = (const float*)d_in[9];
  a.Wr     = (const float*)d_in[10];
  a.bng    = (const float*)d_in[11];
  a.bnb    = (const float*)d_in[12];
  a.bnm    = (const float*)d_in[13];
  a.bnv    = (const float*)d_in[14];
  a.cnt    = zreg;
  a.cur    = zreg + N;
  a.cursor = zreg + 2 * N;
  a.rowbeg = rowbeg;
  a.col    = col;
  a.Bfm    = Bfm;
  a.hA     = hA;
  a.hB     = hB;
  a.agg    = agg;
  a.out    = (float*)d_out;
  a.N  = N;
  a.E  = E;
  a.NB = (N + 255) / 256;
  a.EB = (E + 255) / 256;
  a.GB = (N + 63) / 64;
  a.NG = (N + 7) / 8;

  // Cooperative grid: max co-resident blocks for this kernel (host-side query,
  // graph-capture-safe; cached). MI355X has 256 CUs.
  static int s_grid = 0;
  if (s_grid == 0) {
    int nb = 0;
    hipError_t err = hipOccupancyMaxActiveBlocksPerMultiprocessor(&nb, mega, 256, 0);
    if (err != hipSuccess || nb < 1) nb = 2;
    if (nb > 8) nb = 8;
    s_grid = nb * 256;
  }

  void* kargs[] = { (void*)&a };
  hipLaunchCooperativeKernel((const void*)mega, dim3(s_grid), dim3(256), kargs, 0, stream);
}

// Round 7
// 437.776 us; speedup vs baseline: 2.8943x; 2.8943x over previous
//
#include <hip/hip_runtime.h>

#define BN_EPS 1e-5f

typedef __bf16 bf16x8 __attribute__((ext_vector_type(8)));
typedef float f32x4 __attribute__((ext_vector_type(4)));
typedef unsigned int uint;
typedef unsigned short ushort;

__device__ __forceinline__ ushort f2bf(float f) {
  union { float f; uint u; } v; v.f = f;
  uint r = v.u + 0x7FFF + ((v.u >> 16) & 1);   // RNE
  return (ushort)(r >> 16);
}
__device__ __forceinline__ float bf2f_lo(uint u) {
  union { uint i; float f; } v; v.i = u << 16; return v.f;
}
__device__ __forceinline__ float bf2f_hi(uint u) {
  union { uint i; float f; } v; v.i = u & 0xffff0000u; return v.f;
}
__device__ __forceinline__ uint pack2(float a, float b) {
  return (uint)f2bf(a) | ((uint)f2bf(b) << 16);
}

// ---------------- weight prep: split-K fragment-major bf16 ----------------
// MUST run before any GEMM that reads Bfm (round-6 lesson: ordering!).

__global__ void prep_weights_fm(const float* __restrict__ W_in, const float* __restrict__ Wl,
                                const float* __restrict__ Wr, ushort* __restrict__ Bfm) {
  int p = blockIdx.x * 256 + threadIdx.x;
  int mat = p >> 12;
  int rem = p & 4095;
  int half = rem >> 11;
  int rem2 = rem & 2047;
  int nt = rem2 >> 8, kt2 = (rem2 >> 6) & 3, lane = rem2 & 63;
  int n = nt * 16 + (lane & 15);
  int k0 = (half * 4 + kt2) * 32 + (lane >> 4) * 8;
  ushort tmp[8];
  #pragma unroll
  for (int j = 0; j < 8; ++j) {
    int k = k0 + j;
    float v;
    if (mat == 0) v = W_in[k * 128 + n];
    else {
      int l = mat - 1;
      v = (k < 128) ? Wl[l * 16384 + k * 128 + n] : Wr[l * 16384 + (k - 128) * 128 + n];
    }
    tmp[j] = f2bf(v);
  }
  *(uint4*)&Bfm[(size_t)p * 8] = *(const uint4*)tmp;
}

// ---------------- CSR build (bump allocation) ----------------

// Reserve contiguous CSR ranges via wave-scan + single-cursor atomic bump
// (row order across nodes is irrelevant — only per-node [beg, beg+deg) matters).
__global__ void reserve_kernel(const int* __restrict__ cnt, int* __restrict__ rowbeg,
                               int* __restrict__ cursor, int N) {
  int tid = threadIdx.x;
  int i = blockIdx.x * 256 + tid;
  int v = (i < N) ? cnt[i] : 0;
  int lane = tid & 63;
  int x = v;
  #pragma unroll
  for (int off = 1; off < 64; off <<= 1) {
    int y = __shfl_up(x, off, 64);
    if (lane >= off) x += y;
  }
  int ret = 0;
  if (lane == 63) ret = atomicAdd(cursor, x);
  int base = __shfl(ret, 63);
  if (i < N) rowbeg[i] = base + x - v;
}

__global__ void fill_kernel(const int* __restrict__ src, const int* __restrict__ dst,
                            const int* __restrict__ rowbeg, int* __restrict__ cur,
                            int* __restrict__ col, int E) {
  int e = blockIdx.x * 256 + threadIdx.x;
  if (e < E) {
    int d = dst[e];
    int p = rowbeg[d] + atomicAdd(&cur[d], 1);
    col[p] = src[e];
  }
}

// ---------------- mean aggregation: 2 nodes per wave, fully predicated ----
// Single 4-wide predicated loop: all 4 row loads always in flight (clamped
// col index, zeroed contribution for out-of-range edges) — no serial 1-wide
// tail. Numerically identical to the tailed version (zeros add nothing).

__global__ void agg_kernel(const int* __restrict__ rowbeg, const int* __restrict__ deg,
                           const int* __restrict__ col,
                           const ushort* __restrict__ h, ushort* __restrict__ agg, int N) {
  int node = blockIdx.x * 8 + (threadIdx.x >> 5);
  if (node >= N) return;
  int lane = threadIdx.x & 31;
  const ushort* hp = h + lane * 4;
  int beg = rowbeg[node];
  int d = deg[node];
  float di = 1.0f / (float)(d > 0 ? d : 1);
  int end = beg + d;
  float a0 = 0.f, a1 = 0.f, a2 = 0.f, a3 = 0.f;
  #pragma unroll 1
  for (int e = beg; e < end; e += 4) {
    int i1 = e + 1, i2 = e + 2, i3 = e + 3;
    int c0 = col[e];
    int c1 = col[i1 < end ? i1 : e];
    int c2 = col[i2 < end ? i2 : e];
    int c3 = col[i3 < end ? i3 : e];
    uint2 v0 = *(const uint2*)(hp + (size_t)c0 * 128);
    uint2 v1 = *(const uint2*)(hp + (size_t)c1 * 128);
    uint2 v2 = *(const uint2*)(hp + (size_t)c2 * 128);
    uint2 v3 = *(const uint2*)(hp + (size_t)c3 * 128);
    if (i1 >= end) { v1.x = 0u; v1.y = 0u; }
    if (i2 >= end) { v2.x = 0u; v2.y = 0u; }
    if (i3 >= end) { v3.x = 0u; v3.y = 0u; }
    a0 += (bf2f_lo(v0.x) + bf2f_lo(v1.x)) + (bf2f_lo(v2.x) + bf2f_lo(v3.x));
    a1 += (bf2f_hi(v0.x) + bf2f_hi(v1.x)) + (bf2f_hi(v2.x) + bf2f_hi(v3.x));
    a2 += (bf2f_lo(v0.y) + bf2f_lo(v1.y)) + (bf2f_lo(v2.y) + bf2f_lo(v3.y));
    a3 += (bf2f_hi(v0.y) + bf2f_hi(v1.y)) + (bf2f_hi(v2.y) + bf2f_hi(v3.y));
  }
  uint2 o;
  o.x = pack2(a0 * di, a1 * di);
  o.y = pack2(a2 * di, a3 * di);
  *(uint2*)(agg + (size_t)node * 128 + lane * 4) = o;
}

// ---------------- MFMA GEMM (layers): BM=64, barrier-free ---------------------

template<bool F32OUT>
__global__ __launch_bounds__(256, 4)
void gemm_layer(const ushort* __restrict__ A0, const ushort* __restrict__ A1,
                const ushort* __restrict__ Bfm, const float* __restrict__ bias,
                const float* __restrict__ gamma, const float* __restrict__ beta,
                const float* __restrict__ mean, const float* __restrict__ var,
                const ushort* __restrict__ residual, void* __restrict__ out, int N) {
  __shared__ float Cb_all[4 * 16 * 68];
  int tid = threadIdx.x, wave = tid >> 6, lane = tid & 63;
  int wm = wave >> 1, wn = wave & 1, quad = lane >> 4, l16 = lane & 15;
  int m0 = blockIdx.x * 64;

  int rowm[2];
  #pragma unroll
  for (int mt = 0; mt < 2; ++mt) {
    int r = m0 + wm * 32 + mt * 16 + l16;
    rowm[mt] = r < N ? r : N - 1;
  }

  uint4 a_buf[2][2], b_buf[2][4];
  #pragma unroll
  for (int mt = 0; mt < 2; ++mt)
    a_buf[0][mt] = *(const uint4*)(A0 + (size_t)rowm[mt] * 128 + quad * 8);
  {
    const ushort* bp = Bfm + (size_t)(wn * 4 * 256 + lane) * 8;
    #pragma unroll
    for (int nt = 0; nt < 4; ++nt)
      b_buf[0][nt] = *(const uint4*)(bp + nt * 2048);
  }

  f32x4 acc[2][4] = {};

  #pragma unroll
  for (int kt = 0; kt < 8; ++kt) {
    if (kt < 7) {
      int k1 = kt + 1;
      const ushort* bse = (k1 < 4) ? A0 : A1;
      int ko = (k1 & 3) * 32 + quad * 8;
      #pragma unroll
      for (int mt = 0; mt < 2; ++mt)
        a_buf[k1 & 1][mt] = *(const uint4*)(bse + (size_t)rowm[mt] * 128 + ko);
      const ushort* bp = Bfm + ((size_t)(k1 >> 2) * 16384 +
                                (size_t)((wn * 4) * 256 + (k1 & 3) * 64 + lane) * 8);
      #pragma unroll
      for (int nt = 0; nt < 4; ++nt)
        b_buf[k1 & 1][nt] = *(const uint4*)(bp + nt * 2048);
    }
    __builtin_amdgcn_sched_barrier(0);   // loads stay issued ahead of the MFMAs
    #pragma unroll
    for (int mt = 0; mt < 2; ++mt) {
      bf16x8 af = __builtin_bit_cast(bf16x8, a_buf[kt & 1][mt]);
      #pragma unroll
      for (int nt = 0; nt < 4; ++nt)
        acc[mt][nt] = __builtin_amdgcn_mfma_f32_16x16x32_bf16(
            af, __builtin_bit_cast(bf16x8, b_buf[kt & 1][nt]), acc[mt][nt], 0, 0, 0);
    }
  }

  // bias + BN + ReLU in registers
  #pragma unroll
  for (int nt = 0; nt < 4; ++nt) {
    int c = wn * 64 + nt * 16 + l16;
    float sc = gamma[c] * rsqrtf(var[c] + BN_EPS);
    float sh = beta[c] - mean[c] * sc;
    float bi = bias[c];
    #pragma unroll
    for (int mt = 0; mt < 2; ++mt)
      #pragma unroll
      for (int r = 0; r < 4; ++r)
        acc[mt][nt][r] = fmaxf((acc[mt][nt][r] + bi) * sc + sh, 0.f);
  }

  // per-wave LDS bounce for vectorized residual+store (no barriers)
  float* Cb = Cb_all + wave * (16 * 68);
  #pragma unroll
  for (int mt = 0; mt < 2; ++mt) {
    #pragma unroll
    for (int nt = 0; nt < 4; ++nt)
      #pragma unroll
      for (int r = 0; r < 4; ++r)
        Cb[(quad * 4 + r) * 68 + nt * 16 + l16] = acc[mt][nt][r];
    #pragma unroll
    for (int i = 0; i < 4; ++i) {
      int idx = i * 64 + lane, rowl = idx >> 4, seg = idx & 15;
      int grow = m0 + wm * 32 + mt * 16 + rowl;
      if (grow < N) {
        float4 vv = *(float4*)&Cb[rowl * 68 + seg * 4];
        uint2 rv = *(const uint2*)(residual + (size_t)grow * 128 + wn * 64 + seg * 4);
        vv.x += bf2f_lo(rv.x); vv.y += bf2f_hi(rv.x);
        vv.z += bf2f_lo(rv.y); vv.w += bf2f_hi(rv.y);
        if (F32OUT) {
          *(float4*)((float*)out + (size_t)grow * 128 + wn * 64 + seg * 4) = vv;
        } else {
          uint2 o;
          o.x = pack2(vv.x, vv.y); o.y = pack2(vv.z, vv.w);
          *(uint2*)((ushort*)out + (size_t)grow * 128 + wn * 64 + seg * 4) = o;
        }
      }
    }
  }
}

// ---------------- MFMA GEMM (input proj) UNION edge histogram ----------------
// Blocks [0, GB): gemm_in tiles (x fp32 read, latency-bound). Blocks [GB, GB+EB):
// hist chunks (atomicAdd on cnt). Independent outputs (hA vs cnt), both bodies
// barrier-free, so one oversubscribed launch co-schedules them and the ~25 us
// histogram hides under the X stream. Bfm is prepped by the PRIOR dispatch.

__global__ __launch_bounds__(256, 4)
void gemm_in_hist(const float* __restrict__ X, const ushort* __restrict__ Bfm,
                  const float* __restrict__ bias,
                  const float* __restrict__ gamma, const float* __restrict__ beta,
                  const float* __restrict__ mean, const float* __restrict__ var,
                  ushort* __restrict__ out,
                  const int* __restrict__ dst, int* __restrict__ cnt,
                  int N, int E, int GB) {
  __shared__ float Cb_all[4 * 16 * 68];
  if (blockIdx.x >= GB) {
    int e = (blockIdx.x - GB) * 256 + threadIdx.x;
    if (e < E) atomicAdd(&cnt[dst[e]], 1);
    return;
  }
  int tid = threadIdx.x, wave = tid >> 6, lane = tid & 63;
  int wm = wave >> 1, wn = wave & 1, quad = lane >> 4, l16 = lane & 15;
  int m0 = blockIdx.x * 64;

  int rowm[2];
  #pragma unroll
  for (int mt = 0; mt < 2; ++mt) {
    int r = m0 + wm * 32 + mt * 16 + l16;
    rowm[mt] = r < N ? r : N - 1;
  }

  float4 f_buf[2][2][2];
  uint4 b_buf[2][4];
  #pragma unroll
  for (int mt = 0; mt < 2; ++mt) {
    const float* p = X + (size_t)rowm[mt] * 256 + quad * 8;
    f_buf[0][mt][0] = *(const float4*)p;
    f_buf[0][mt][1] = *(const float4*)(p + 4);
  }
  {
    const ushort* bp = Bfm + (size_t)(wn * 4 * 256 + lane) * 8;
    #pragma unroll
    for (int nt = 0; nt < 4; ++nt)
      b_buf[0][nt] = *(const uint4*)(bp + nt * 2048);
  }

  f32x4 acc[2][4] = {};

  #pragma unroll
  for (int kt = 0; kt < 8; ++kt) {
    if (kt < 7) {
      int k1 = kt + 1;
      int ko = k1 * 32 + quad * 8;
      #pragma unroll
      for (int mt = 0; mt < 2; ++mt) {
        const float* p = X + (size_t)rowm[mt] * 256 + ko;
        f_buf[k1 & 1][mt][0] = *(const float4*)p;
        f_buf[k1 & 1][mt][1] = *(const float4*)(p + 4);
      }
      const ushort* bp = Bfm + ((size_t)(k1 >> 2) * 16384 +
                                (size_t)((wn * 4) * 256 + (k1 & 3) * 64 + lane) * 8);
      #pragma unroll
      for (int nt = 0; nt < 4; ++nt)
        b_buf[k1 & 1][nt] = *(const uint4*)(bp + nt * 2048);
    }
    __builtin_amdgcn_sched_barrier(0);
    #pragma unroll
    for (int mt = 0; mt < 2; ++mt) {
      float4 lo = f_buf[kt & 1][mt][0], hi = f_buf[kt & 1][mt][1];
      uint4 av;
      av.x = pack2(lo.x, lo.y); av.y = pack2(lo.z, lo.w);
      av.z = pack2(hi.x, hi.y); av.w = pack2(hi.z, hi.w);
      bf16x8 af = __builtin_bit_cast(bf16x8, av);
      #pragma unroll
      for (int nt = 0; nt < 4; ++nt)
        acc[mt][nt] = __builtin_amdgcn_mfma_f32_16x16x32_bf16(
            af, __builtin_bit_cast(bf16x8, b_buf[kt & 1][nt]), acc[mt][nt], 0, 0, 0);
    }
  }

  #pragma unroll
  for (int nt = 0; nt < 4; ++nt) {
    int c = wn * 64 + nt * 16 + l16;
    float sc = gamma[c] * rsqrtf(var[c] + BN_EPS);
    float sh = beta[c] - mean[c] * sc;
    float bi = bias[c];
    #pragma unroll
    for (int mt = 0; mt < 2; ++mt)
      #pragma unroll
      for (int r = 0; r < 4; ++r)
        acc[mt][nt][r] = fmaxf((acc[mt][nt][r] + bi) * sc + sh, 0.f);
  }

  float* Cb = Cb_all + wave * (16 * 68);
  #pragma unroll
  for (int mt = 0; mt < 2; ++mt) {
    #pragma unroll
    for (int nt = 0; nt < 4; ++nt)
      #pragma unroll
      for (int r = 0; r < 4; ++r)
        Cb[(quad * 4 + r) * 68 + nt * 16 + l16] = acc[mt][nt][r];
    #pragma unroll
    for (int i = 0; i < 4; ++i) {
      int idx = i * 64 + lane, rowl = idx >> 4, seg = idx & 15;
      int grow = m0 + wm * 32 + mt * 16 + rowl;
      if (grow < N) {
        float4 vv = *(float4*)&Cb[rowl * 68 + seg * 4];
        uint2 o;
        o.x = pack2(vv.x, vv.y); o.y = pack2(vv.z, vv.w);
        *(uint2*)(out + (size_t)grow * 128 + wn * 64 + seg * 4) = o;
      }
    }
  }
}

// ---------------- launch ----------------

extern "C" void kernel_launch(void* const* d_in, const int* in_sizes, int n_in,
                              void* d_out, int out_size, void* d_ws, size_t ws_size,
                              hipStream_t stream) {
  const float* x      = (const float*)d_in[0];
  const int*   eidx   = (const int*)d_in[1];
  const float* W_in   = (const float*)d_in[2];
  const float* b_in   = (const float*)d_in[3];
  const float* bng_in = (const float*)d_in[4];
  const float* bnb_in = (const float*)d_in[5];
  const float* bnm_in = (const float*)d_in[6];
  const float* bnv_in = (const float*)d_in[7];
  const float* Wl     = (const float*)d_in[8];
  const float* bl     = (const float*)d_in[9];
  const float* Wr     = (const float*)d_in[10];
  const float* bng    = (const float*)d_in[11];
  const float* bnb    = (const float*)d_in[12];
  const float* bnm    = (const float*)d_in[13];
  const float* bnv    = (const float*)d_in[14];

  const int N = in_sizes[0] / 256;
  const int E = in_sizes[1] / 2;
  const int NB = (N + 255) / 256;
  const int* src = eidx;
  const int* dst = eidx + E;

  char* ws = (char*)d_ws;
  size_t off = 0;
  auto alloc = [&](size_t bytes) {
    void* p = ws + off;
    off = (off + bytes + 255) & ~(size_t)255;
    return p;
  };
  int* zreg     = (int*)alloc((size_t)(2 * N + 1) * 4);   // cnt(deg) | cur | cursor
  int* cnt      = zreg;
  int* cur      = zreg + N;
  int* cursor   = zreg + 2 * N;
  int* rowbeg   = (int*)alloc((size_t)N * 4);
  int* col      = (int*)alloc((size_t)E * 4);
  ushort* Bfm   = (ushort*)alloc(4 * 32768 * 2);   // split-K frag-major: [in, l0, l1, l2]
  ushort* hA    = (ushort*)alloc((size_t)N * 128 * 2);
  ushort* hB    = (ushort*)alloc((size_t)N * 128 * 2);
  ushort* agg   = (ushort*)alloc((size_t)N * 128 * 2);
  (void)ws_size; (void)n_in; (void)out_size;

  const int EB = (E + 255) / 256;
  const int GB = (N + 63) / 64;

  // counters zero + weight prep (Bfm MUST be ready before gemm_in_hist)
  hipMemsetAsync(zreg, 0, (size_t)(2 * N + 1) * 4, stream);
  prep_weights_fm<<<64, 256, 0, stream>>>(W_in, Wl, Wr, Bfm);

  // input projection UNION edge histogram (independent outputs)
  gemm_in_hist<<<GB + EB, 256, 0, stream>>>(x, Bfm, b_in, bng_in, bnb_in, bnm_in, bnv_in,
                                            hA, dst, cnt, N, E, GB);

  // CSR range reserve (bump allocation), then fill
  reserve_kernel<<<NB, 256, 0, stream>>>(cnt, rowbeg, cursor, N);
  fill_kernel<<<EB, 256, 0, stream>>>(src, dst, rowbeg, cur, col, E);

  // 3 SAGE layers: hA -> hB -> hA -> d_out(fp32)
  ushort* hbuf[2] = { hA, hB };
  for (int l = 0; l < 3; ++l) {
    const ushort* h_in = hbuf[l & 1];
    agg_kernel<<<(N + 7) / 8, 256, 0, stream>>>(rowbeg, cnt, col, h_in, agg, N);
    const ushort* BfmL = Bfm + (size_t)(l + 1) * 32768;
    const float* biasL = bl + l * 128;
    if (l < 2) {
      gemm_layer<false><<<GB, 256, 0, stream>>>(agg, h_in, BfmL, biasL,
          bng + l * 128, bnb + l * 128, bnm + l * 128, bnv + l * 128,
          h_in, (void*)hbuf[(l + 1) & 1], N);
    } else {
      gemm_layer<true><<<GB, 256, 0, stream>>>(agg, h_in, BfmL, biasL,
          bng + l * 128, bnb + l * 128, bnm + l * 128, bnv + l * 128,
          h_in, d_out, N);
    }
  }
}

// Round 8
// 432.792 us; speedup vs baseline: 2.9276x; 1.0115x over previous
//
#include <hip/hip_runtime.h>

#define BN_EPS 1e-5f

typedef __bf16 bf16x8 __attribute__((ext_vector_type(8)));
typedef float f32x4 __attribute__((ext_vector_type(4)));
typedef unsigned int uint;
typedef unsigned short ushort;

__device__ __forceinline__ ushort f2bf(float f) {
  union { float f; uint u; } v; v.f = f;
  uint r = v.u + 0x7FFF + ((v.u >> 16) & 1);   // RNE
  return (ushort)(r >> 16);
}
__device__ __forceinline__ float bf2f_lo(uint u) {
  union { uint i; float f; } v; v.i = u << 16; return v.f;
}
__device__ __forceinline__ float bf2f_hi(uint u) {
  union { uint i; float f; } v; v.i = u & 0xffff0000u; return v.f;
}
__device__ __forceinline__ uint pack2(float a, float b) {
  return (uint)f2bf(a) | ((uint)f2bf(b) << 16);
}

// ---------------- weight prep: split-K fragment-major bf16 ----------------
// MUST run before any GEMM that reads Bfm (round-6 lesson: ordering!).

__global__ void prep_weights_fm(const float* __restrict__ W_in, const float* __restrict__ Wl,
                                const float* __restrict__ Wr, ushort* __restrict__ Bfm) {
  int p = blockIdx.x * 256 + threadIdx.x;
  int mat = p >> 12;
  int rem = p & 4095;
  int half = rem >> 11;
  int rem2 = rem & 2047;
  int nt = rem2 >> 8, kt2 = (rem2 >> 6) & 3, lane = rem2 & 63;
  int n = nt * 16 + (lane & 15);
  int k0 = (half * 4 + kt2) * 32 + (lane >> 4) * 8;
  ushort tmp[8];
  #pragma unroll
  for (int j = 0; j < 8; ++j) {
    int k = k0 + j;
    float v;
    if (mat == 0) v = W_in[k * 128 + n];
    else {
      int l = mat - 1;
      v = (k < 128) ? Wl[l * 16384 + k * 128 + n] : Wr[l * 16384 + (k - 128) * 128 + n];
    }
    tmp[j] = f2bf(v);
  }
  *(uint4*)&Bfm[(size_t)p * 8] = *(const uint4*)tmp;
}

// ---------------- CSR build (bump allocation) ----------------

// Reserve contiguous CSR ranges via wave-scan + single-cursor atomic bump
// (row order across nodes is irrelevant — only per-node [beg, beg+deg) matters).
__global__ void reserve_kernel(const int* __restrict__ cnt, int* __restrict__ rowbeg,
                               int* __restrict__ cursor, int N) {
  int tid = threadIdx.x;
  int i = blockIdx.x * 256 + tid;
  int v = (i < N) ? cnt[i] : 0;
  int lane = tid & 63;
  int x = v;
  #pragma unroll
  for (int off = 1; off < 64; off <<= 1) {
    int y = __shfl_up(x, off, 64);
    if (lane >= off) x += y;
  }
  int ret = 0;
  if (lane == 63) ret = atomicAdd(cursor, x);
  int base = __shfl(ret, 63);
  if (i < N) rowbeg[i] = base + x - v;
}

__global__ void fill_kernel(const int* __restrict__ src, const int* __restrict__ dst,
                            const int* __restrict__ rowbeg, int* __restrict__ cur,
                            int* __restrict__ col, int E) {
  int e = blockIdx.x * 256 + threadIdx.x;
  if (e < E) {
    int d = dst[e];
    int p = rowbeg[d] + atomicAdd(&cur[d], 1);
    col[p] = src[e];
  }
}

// ---------------- mean aggregation: quarter-wave per node, 8-wide gather ---
// 16 lanes x uint4 = the full 256-B row in ONE coalesced instruction
// (16 B/lane, 2x the bytes/instr of the old half-wave uint2 shape). 8 row
// loads in flight per node; avg deg 6.4 => ~80% of nodes finish in a single
// load round (vs ~2 rounds at 4-wide). Fully predicated tail (clamped col
// index + zeroed contribution — numerically a no-op). 16 nodes/block.

__global__ void agg_kernel(const int* __restrict__ rowbeg, const int* __restrict__ deg,
                           const int* __restrict__ col,
                           const ushort* __restrict__ h, ushort* __restrict__ agg, int N) {
  int node = blockIdx.x * 16 + (threadIdx.x >> 4);
  if (node >= N) return;
  int lane = threadIdx.x & 15;
  const ushort* hp = h + lane * 8;
  int beg = rowbeg[node];
  int d = deg[node];
  float di = 1.0f / (float)(d > 0 ? d : 1);
  int end = beg + d;
  float a0 = 0.f, a1 = 0.f, a2 = 0.f, a3 = 0.f;
  float a4 = 0.f, a5 = 0.f, a6 = 0.f, a7 = 0.f;
  #pragma unroll 1
  for (int e = beg; e < end; e += 8) {
    int cc[8];
    #pragma unroll
    for (int j = 0; j < 8; ++j) {
      int idx = e + j;
      cc[j] = col[idx < end ? idx : e];
    }
    uint4 v[8];
    #pragma unroll
    for (int j = 0; j < 8; ++j)
      v[j] = *(const uint4*)(hp + (size_t)cc[j] * 128);
    #pragma unroll
    for (int j = 1; j < 8; ++j)
      if (e + j >= end) { v[j].x = 0u; v[j].y = 0u; v[j].z = 0u; v[j].w = 0u; }
    #pragma unroll
    for (int j = 0; j < 8; ++j) {
      a0 += bf2f_lo(v[j].x); a1 += bf2f_hi(v[j].x);
      a2 += bf2f_lo(v[j].y); a3 += bf2f_hi(v[j].y);
      a4 += bf2f_lo(v[j].z); a5 += bf2f_hi(v[j].z);
      a6 += bf2f_lo(v[j].w); a7 += bf2f_hi(v[j].w);
    }
  }
  uint4 o;
  o.x = pack2(a0 * di, a1 * di);
  o.y = pack2(a2 * di, a3 * di);
  o.z = pack2(a4 * di, a5 * di);
  o.w = pack2(a6 * di, a7 * di);
  *(uint4*)(agg + (size_t)node * 128 + lane * 8) = o;
}

// ---------------- MFMA GEMM (layers): BM=64, barrier-free ---------------------

template<bool F32OUT>
__global__ __launch_bounds__(256, 4)
void gemm_layer(const ushort* __restrict__ A0, const ushort* __restrict__ A1,
                const ushort* __restrict__ Bfm, const float* __restrict__ bias,
                const float* __restrict__ gamma, const float* __restrict__ beta,
                const float* __restrict__ mean, const float* __restrict__ var,
                const ushort* __restrict__ residual, void* __restrict__ out, int N) {
  __shared__ float Cb_all[4 * 16 * 68];
  int tid = threadIdx.x, wave = tid >> 6, lane = tid & 63;
  int wm = wave >> 1, wn = wave & 1, quad = lane >> 4, l16 = lane & 15;
  int m0 = blockIdx.x * 64;

  int rowm[2];
  #pragma unroll
  for (int mt = 0; mt < 2; ++mt) {
    int r = m0 + wm * 32 + mt * 16 + l16;
    rowm[mt] = r < N ? r : N - 1;
  }

  uint4 a_buf[2][2], b_buf[2][4];
  #pragma unroll
  for (int mt = 0; mt < 2; ++mt)
    a_buf[0][mt] = *(const uint4*)(A0 + (size_t)rowm[mt] * 128 + quad * 8);
  {
    const ushort* bp = Bfm + (size_t)(wn * 4 * 256 + lane) * 8;
    #pragma unroll
    for (int nt = 0; nt < 4; ++nt)
      b_buf[0][nt] = *(const uint4*)(bp + nt * 2048);
  }

  f32x4 acc[2][4] = {};

  #pragma unroll
  for (int kt = 0; kt < 8; ++kt) {
    if (kt < 7) {
      int k1 = kt + 1;
      const ushort* bse = (k1 < 4) ? A0 : A1;
      int ko = (k1 & 3) * 32 + quad * 8;
      #pragma unroll
      for (int mt = 0; mt < 2; ++mt)
        a_buf[k1 & 1][mt] = *(const uint4*)(bse + (size_t)rowm[mt] * 128 + ko);
      const ushort* bp = Bfm + ((size_t)(k1 >> 2) * 16384 +
                                (size_t)((wn * 4) * 256 + (k1 & 3) * 64 + lane) * 8);
      #pragma unroll
      for (int nt = 0; nt < 4; ++nt)
        b_buf[k1 & 1][nt] = *(const uint4*)(bp + nt * 2048);
    }
    __builtin_amdgcn_sched_barrier(0);   // loads stay issued ahead of the MFMAs
    #pragma unroll
    for (int mt = 0; mt < 2; ++mt) {
      bf16x8 af = __builtin_bit_cast(bf16x8, a_buf[kt & 1][mt]);
      #pragma unroll
      for (int nt = 0; nt < 4; ++nt)
        acc[mt][nt] = __builtin_amdgcn_mfma_f32_16x16x32_bf16(
            af, __builtin_bit_cast(bf16x8, b_buf[kt & 1][nt]), acc[mt][nt], 0, 0, 0);
    }
  }

  // bias + BN + ReLU in registers
  #pragma unroll
  for (int nt = 0; nt < 4; ++nt) {
    int c = wn * 64 + nt * 16 + l16;
    float sc = gamma[c] * rsqrtf(var[c] + BN_EPS);
    float sh = beta[c] - mean[c] * sc;
    float bi = bias[c];
    #pragma unroll
    for (int mt = 0; mt < 2; ++mt)
      #pragma unroll
      for (int r = 0; r < 4; ++r)
        acc[mt][nt][r] = fmaxf((acc[mt][nt][r] + bi) * sc + sh, 0.f);
  }

  // per-wave LDS bounce for vectorized residual+store (no barriers)
  float* Cb = Cb_all + wave * (16 * 68);
  #pragma unroll
  for (int mt = 0; mt < 2; ++mt) {
    #pragma unroll
    for (int nt = 0; nt < 4; ++nt)
      #pragma unroll
      for (int r = 0; r < 4; ++r)
        Cb[(quad * 4 + r) * 68 + nt * 16 + l16] = acc[mt][nt][r];
    #pragma unroll
    for (int i = 0; i < 4; ++i) {
      int idx = i * 64 + lane, rowl = idx >> 4, seg = idx & 15;
      int grow = m0 + wm * 32 + mt * 16 + rowl;
      if (grow < N) {
        float4 vv = *(float4*)&Cb[rowl * 68 + seg * 4];
        uint2 rv = *(const uint2*)(residual + (size_t)grow * 128 + wn * 64 + seg * 4);
        vv.x += bf2f_lo(rv.x); vv.y += bf2f_hi(rv.x);
        vv.z += bf2f_lo(rv.y); vv.w += bf2f_hi(rv.y);
        if (F32OUT) {
          *(float4*)((float*)out + (size_t)grow * 128 + wn * 64 + seg * 4) = vv;
        } else {
          uint2 o;
          o.x = pack2(vv.x, vv.y); o.y = pack2(vv.z, vv.w);
          *(uint2*)((ushort*)out + (size_t)grow * 128 + wn * 64 + seg * 4) = o;
        }
      }
    }
  }
}

// ---------------- MFMA GEMM (input proj) UNION edge histogram ----------------
// Blocks [0, GB): gemm_in tiles (x fp32 read, latency-bound). Blocks [GB, GB+EB):
// hist chunks (atomicAdd on cnt). Independent outputs (hA vs cnt), both bodies
// barrier-free, so one oversubscribed launch co-schedules them and the ~25 us
// histogram hides under the X stream. Bfm is prepped by the PRIOR dispatch.

__global__ __launch_bounds__(256, 4)
void gemm_in_hist(const float* __restrict__ X, const ushort* __restrict__ Bfm,
                  const float* __restrict__ bias,
                  const float* __restrict__ gamma, const float* __restrict__ beta,
                  const float* __restrict__ mean, const float* __restrict__ var,
                  ushort* __restrict__ out,
                  const int* __restrict__ dst, int* __restrict__ cnt,
                  int N, int E, int GB) {
  __shared__ float Cb_all[4 * 16 * 68];
  if (blockIdx.x >= GB) {
    int e = (blockIdx.x - GB) * 256 + threadIdx.x;
    if (e < E) atomicAdd(&cnt[dst[e]], 1);
    return;
  }
  int tid = threadIdx.x, wave = tid >> 6, lane = tid & 63;
  int wm = wave >> 1, wn = wave & 1, quad = lane >> 4, l16 = lane & 15;
  int m0 = blockIdx.x * 64;

  int rowm[2];
  #pragma unroll
  for (int mt = 0; mt < 2; ++mt) {
    int r = m0 + wm * 32 + mt * 16 + l16;
    rowm[mt] = r < N ? r : N - 1;
  }

  float4 f_buf[2][2][2];
  uint4 b_buf[2][4];
  #pragma unroll
  for (int mt = 0; mt < 2; ++mt) {
    const float* p = X + (size_t)rowm[mt] * 256 + quad * 8;
    f_buf[0][mt][0] = *(const float4*)p;
    f_buf[0][mt][1] = *(const float4*)(p + 4);
  }
  {
    const ushort* bp = Bfm + (size_t)(wn * 4 * 256 + lane) * 8;
    #pragma unroll
    for (int nt = 0; nt < 4; ++nt)
      b_buf[0][nt] = *(const uint4*)(bp + nt * 2048);
  }

  f32x4 acc[2][4] = {};

  #pragma unroll
  for (int kt = 0; kt < 8; ++kt) {
    if (kt < 7) {
      int k1 = kt + 1;
      int ko = k1 * 32 + quad * 8;
      #pragma unroll
      for (int mt = 0; mt < 2; ++mt) {
        const float* p = X + (size_t)rowm[mt] * 256 + ko;
        f_buf[k1 & 1][mt][0] = *(const float4*)p;
        f_buf[k1 & 1][mt][1] = *(const float4*)(p + 4);
      }
      const ushort* bp = Bfm + ((size_t)(k1 >> 2) * 16384 +
                                (size_t)((wn * 4) * 256 + (k1 & 3) * 64 + lane) * 8);
      #pragma unroll
      for (int nt = 0; nt < 4; ++nt)
        b_buf[k1 & 1][nt] = *(const uint4*)(bp + nt * 2048);
    }
    __builtin_amdgcn_sched_barrier(0);
    #pragma unroll
    for (int mt = 0; mt < 2; ++mt) {
      float4 lo = f_buf[kt & 1][mt][0], hi = f_buf[kt & 1][mt][1];
      uint4 av;
      av.x = pack2(lo.x, lo.y); av.y = pack2(lo.z, lo.w);
      av.z = pack2(hi.x, hi.y); av.w = pack2(hi.z, hi.w);
      bf16x8 af = __builtin_bit_cast(bf16x8, av);
      #pragma unroll
      for (int nt = 0; nt < 4; ++nt)
        acc[mt][nt] = __builtin_amdgcn_mfma_f32_16x16x32_bf16(
            af, __builtin_bit_cast(bf16x8, b_buf[kt & 1][nt]), acc[mt][nt], 0, 0, 0);
    }
  }

  #pragma unroll
  for (int nt = 0; nt < 4; ++nt) {
    int c = wn * 64 + nt * 16 + l16;
    float sc = gamma[c] * rsqrtf(var[c] + BN_EPS);
    float sh = beta[c] - mean[c] * sc;
    float bi = bias[c];
    #pragma unroll
    for (int mt = 0; mt < 2; ++mt)
      #pragma unroll
      for (int r = 0; r < 4; ++r)
        acc[mt][nt][r] = fmaxf((acc[mt][nt][r] + bi) * sc + sh, 0.f);
  }

  float* Cb = Cb_all + wave * (16 * 68);
  #pragma unroll
  for (int mt = 0; mt < 2; ++mt) {
    #pragma unroll
    for (int nt = 0; nt < 4; ++nt)
      #pragma unroll
      for (int r = 0; r < 4; ++r)
        Cb[(quad * 4 + r) * 68 + nt * 16 + l16] = acc[mt][nt][r];
    #pragma unroll
    for (int i = 0; i < 4; ++i) {
      int idx = i * 64 + lane, rowl = idx >> 4, seg = idx & 15;
      int grow = m0 + wm * 32 + mt * 16 + rowl;
      if (grow < N) {
        float4 vv = *(float4*)&Cb[rowl * 68 + seg * 4];
        uint2 o;
        o.x = pack2(vv.x, vv.y); o.y = pack2(vv.z, vv.w);
        *(uint2*)(out + (size_t)grow * 128 + wn * 64 + seg * 4) = o;
      }
    }
  }
}

// ---------------- launch ----------------

extern "C" void kernel_launch(void* const* d_in, const int* in_sizes, int n_in,
                              void* d_out, int out_size, void* d_ws, size_t ws_size,
                              hipStream_t stream) {
  const float* x      = (const float*)d_in[0];
  const int*   eidx   = (const int*)d_in[1];
  const float* W_in   = (const float*)d_in[2];
  const float* b_in   = (const float*)d_in[3];
  const float* bng_in = (const float*)d_in[4];
  const float* bnb_in = (const float*)d_in[5];
  const float* bnm_in = (const float*)d_in[6];
  const float* bnv_in = (const float*)d_in[7];
  const float* Wl     = (const float*)d_in[8];
  const float* bl     = (const float*)d_in[9];
  const float* Wr     = (const float*)d_in[10];
  const float* bng    = (const float*)d_in[11];
  const float* bnb    = (const float*)d_in[12];
  const float* bnm    = (const float*)d_in[13];
  const float* bnv    = (const float*)d_in[14];

  const int N = in_sizes[0] / 256;
  const int E = in_sizes[1] / 2;
  const int NB = (N + 255) / 256;
  const int* src = eidx;
  const int* dst = eidx + E;

  char* ws = (char*)d_ws;
  size_t off = 0;
  auto alloc = [&](size_t bytes) {
    void* p = ws + off;
    off = (off + bytes + 255) & ~(size_t)255;
    return p;
  };
  int* zreg     = (int*)alloc((size_t)(2 * N + 1) * 4);   // cnt(deg) | cur | cursor
  int* cnt      = zreg;
  int* cur      = zreg + N;
  int* cursor   = zreg + 2 * N;
  int* rowbeg   = (int*)alloc((size_t)N * 4);
  int* col      = (int*)alloc((size_t)E * 4);
  ushort* Bfm   = (ushort*)alloc(4 * 32768 * 2);   // split-K frag-major: [in, l0, l1, l2]
  ushort* hA    = (ushort*)alloc((size_t)N * 128 * 2);
  ushort* hB    = (ushort*)alloc((size_t)N * 128 * 2);
  ushort* agg   = (ushort*)alloc((size_t)N * 128 * 2);
  (void)ws_size; (void)n_in; (void)out_size;

  const int EB = (E + 255) / 256;
  const int GB = (N + 63) / 64;

  // counters zero + weight prep (Bfm MUST be ready before gemm_in_hist)
  hipMemsetAsync(zreg, 0, (size_t)(2 * N + 1) * 4, stream);
  prep_weights_fm<<<64, 256, 0, stream>>>(W_in, Wl, Wr, Bfm);

  // input projection UNION edge histogram (independent outputs)
  gemm_in_hist<<<GB + EB, 256, 0, stream>>>(x, Bfm, b_in, bng_in, bnb_in, bnm_in, bnv_in,
                                            hA, dst, cnt, N, E, GB);

  // CSR range reserve (bump allocation), then fill
  reserve_kernel<<<NB, 256, 0, stream>>>(cnt, rowbeg, cursor, N);
  fill_kernel<<<EB, 256, 0, stream>>>(src, dst, rowbeg, cur, col, E);

  // 3 SAGE layers: hA -> hB -> hA -> d_out(fp32)
  ushort* hbuf[2] = { hA, hB };
  for (int l = 0; l < 3; ++l) {
    const ushort* h_in = hbuf[l & 1];
    agg_kernel<<<(N + 15) / 16, 256, 0, stream>>>(rowbeg, cnt, col, h_in, agg, N);
    const ushort* BfmL = Bfm + (size_t)(l + 1) * 32768;
    const float* biasL = bl + l * 128;
    if (l < 2) {
      gemm_layer<false><<<GB, 256, 0, stream>>>(agg, h_in, BfmL, biasL,
          bng + l * 128, bnb + l * 128, bnm + l * 128, bnv + l * 128,
          h_in, (void*)hbuf[(l + 1) & 1], N);
    } else {
      gemm_layer<true><<<GB, 256, 0, stream>>>(agg, h_in, BfmL, biasL,
          bng + l * 128, bnb + l * 128, bnm + l * 128, bnv + l * 128,
          h_in, d_out, N);
    }
  }
}

// Round 11
// 425.812 us; speedup vs baseline: 2.9756x; 1.0164x over previous
//
#include <hip/hip_runtime.h>

#define BN_EPS 1e-5f

typedef __bf16 bf16x8 __attribute__((ext_vector_type(8)));
typedef float f32x4 __attribute__((ext_vector_type(4)));
typedef unsigned int uint;
typedef unsigned short ushort;
typedef unsigned char uchar;

__device__ __forceinline__ ushort f2bf(float f) {
  union { float f; uint u; } v; v.f = f;
  uint r = v.u + 0x7FFF + ((v.u >> 16) & 1);   // RNE
  return (ushort)(r >> 16);
}
__device__ __forceinline__ float bf2f_lo(uint u) {
  union { uint i; float f; } v; v.i = u << 16; return v.f;
}
__device__ __forceinline__ float bf2f_hi(uint u) {
  union { uint i; float f; } v; v.i = u & 0xffff0000u; return v.f;
}
__device__ __forceinline__ uint pack2(float a, float b) {
  return (uint)f2bf(a) | ((uint)f2bf(b) << 16);
}

// ---- fp8 e4m3 (non-negative h only; h >= 0 holds inductively: ReLU + residual) ----
// encode: f * 2^-120 puts e4m3's exponent window at f32 bits 20..26;
// RNE via int-add; clamp to 0x7E (=448, e4m3 max; 0x7F is NaN).
__device__ __forceinline__ uint f2e4m3(float f) {
  union { float f; uint u; } v; v.f = f * 0x1p-120f;
  uint r = v.u + 0x7FFFF + ((v.u >> 20) & 1);
  uint u8 = r >> 20;
  return u8 > 0x7Eu ? 0x7Eu : u8;
}
// decode: place 7 magnitude bits at f32 bit 20, scale back by 2^120.
// Exact for e4m3 normals AND subnormals.
__device__ __forceinline__ float e4m32f(uint u8) {
  union { uint u; float f; } v; v.u = (u8 & 0x7Fu) << 20;
  return v.f * 0x1p120f;
}

// ---------------- weight prep: split-K fragment-major bf16 ----------------
// MUST run before any GEMM that reads Bfm (round-6 lesson: ordering!).

__global__ void prep_weights_fm(const float* __restrict__ W_in, const float* __restrict__ Wl,
                                const float* __restrict__ Wr, ushort* __restrict__ Bfm) {
  int p = blockIdx.x * 256 + threadIdx.x;
  int mat = p >> 12;
  int rem = p & 4095;
  int half = rem >> 11;
  int rem2 = rem & 2047;
  int nt = rem2 >> 8, kt2 = (rem2 >> 6) & 3, lane = rem2 & 63;
  int n = nt * 16 + (lane & 15);
  int k0 = (half * 4 + kt2) * 32 + (lane >> 4) * 8;
  ushort tmp[8];
  #pragma unroll
  for (int j = 0; j < 8; ++j) {
    int k = k0 + j;
    float v;
    if (mat == 0) v = W_in[k * 128 + n];
    else {
      int l = mat - 1;
      v = (k < 128) ? Wl[l * 16384 + k * 128 + n] : Wr[l * 16384 + (k - 128) * 128 + n];
    }
    tmp[j] = f2bf(v);
  }
  *(uint4*)&Bfm[(size_t)p * 8] = *(const uint4*)tmp;
}

// ---------------- CSR build (bump allocation) ----------------

__global__ void reserve_kernel(const int* __restrict__ cnt, int* __restrict__ rowbeg,
                               int* __restrict__ cursor, int N) {
  int tid = threadIdx.x;
  int i = blockIdx.x * 256 + tid;
  int v = (i < N) ? cnt[i] : 0;
  int lane = tid & 63;
  int x = v;
  #pragma unroll
  for (int off = 1; off < 64; off <<= 1) {
    int y = __shfl_up(x, off, 64);
    if (lane >= off) x += y;
  }
  int ret = 0;
  if (lane == 63) ret = atomicAdd(cursor, x);
  int base = __shfl(ret, 63);
  if (i < N) rowbeg[i] = base + x - v;
}

__global__ void fill_kernel(const int* __restrict__ src, const int* __restrict__ dst,
                            const int* __restrict__ rowbeg, int* __restrict__ cur,
                            int* __restrict__ col, int E) {
  int e = blockIdx.x * 256 + threadIdx.x;
  if (e < E) {
    int d = dst[e];
    int p = rowbeg[d] + atomicAdd(&cur[d], 1);
    col[p] = src[e];
  }
}

// ---------------- mean aggregation: fp8 gather, quarter-wave per node -----
// Gather reads the fp8 e4m3 shadow of h: 128 B/row = 2 cache lines per edge
// (vs 4 for bf16) — agg was shown line/MSHR-bound (round 8: 8-wide ILP gave
// ~nothing), so halving lines/edge halves the bound. Decode is 3 int ops +
// 1 mul per value; VALU has slack. Output agg stays bf16.

__global__ void agg_kernel(const int* __restrict__ rowbeg, const int* __restrict__ deg,
                           const int* __restrict__ col,
                           const uchar* __restrict__ h8, ushort* __restrict__ agg, int N) {
  int node = blockIdx.x * 16 + (threadIdx.x >> 4);
  if (node >= N) return;
  int lane = threadIdx.x & 15;
  const uchar* hp = h8 + lane * 8;
  int beg = rowbeg[node];
  int d = deg[node];
  float di = 1.0f / (float)(d > 0 ? d : 1);
  int end = beg + d;
  float a0 = 0.f, a1 = 0.f, a2 = 0.f, a3 = 0.f;
  float a4 = 0.f, a5 = 0.f, a6 = 0.f, a7 = 0.f;
  #pragma unroll 1
  for (int e = beg; e < end; e += 8) {
    int cc[8];
    #pragma unroll
    for (int j = 0; j < 8; ++j) {
      int idx = e + j;
      cc[j] = col[idx < end ? idx : e];
    }
    uint2 v[8];
    #pragma unroll
    for (int j = 0; j < 8; ++j)
      v[j] = *(const uint2*)(hp + (size_t)cc[j] * 128);
    #pragma unroll
    for (int j = 1; j < 8; ++j)
      if (e + j >= end) { v[j].x = 0u; v[j].y = 0u; }
    #pragma unroll
    for (int j = 0; j < 8; ++j) {
      a0 += e4m32f(v[j].x);        a1 += e4m32f(v[j].x >> 8);
      a2 += e4m32f(v[j].x >> 16);  a3 += e4m32f(v[j].x >> 24);
      a4 += e4m32f(v[j].y);        a5 += e4m32f(v[j].y >> 8);
      a6 += e4m32f(v[j].y >> 16);  a7 += e4m32f(v[j].y >> 24);
    }
  }
  uint4 o;
  o.x = pack2(a0 * di, a1 * di);
  o.y = pack2(a2 * di, a3 * di);
  o.z = pack2(a4 * di, a5 * di);
  o.w = pack2(a6 * di, a7 * di);
  *(uint4*)(agg + (size_t)node * 128 + lane * 8) = o;
}

// ---------------- MFMA GEMM (layers): BM=64, in-place over A0 -----------------
// WORKSPACE-CRITICAL (rounds 9/10 container deaths = workspace overflow):
// out ALIASES A0 — the epilogue overwrites the agg rows this block consumed,
// eliminating the third 25.6 MB buffer. Each block reads only its own 64 agg
// rows, all consumed in the k-loop; the __syncthreads() before the epilogue
// orders all waves' A0 reads before any wave's store (waves share A-rows but
// write disjoint column halves). Epilogue dual-stores bf16 h + fp8 shadow.

template<bool F32OUT>
__global__ __launch_bounds__(256, 4)
void gemm_layer(const ushort* A0, const ushort* __restrict__ A1,
                const ushort* __restrict__ Bfm, const float* __restrict__ bias,
                const float* __restrict__ gamma, const float* __restrict__ beta,
                const float* __restrict__ mean, const float* __restrict__ var,
                const ushort* residual, void* out,
                uchar* __restrict__ out8, int N) {
  __shared__ float Cb_all[4 * 16 * 68];
  int tid = threadIdx.x, wave = tid >> 6, lane = tid & 63;
  int wm = wave >> 1, wn = wave & 1, quad = lane >> 4, l16 = lane & 15;
  int m0 = blockIdx.x * 64;

  int rowm[2];
  #pragma unroll
  for (int mt = 0; mt < 2; ++mt) {
    int r = m0 + wm * 32 + mt * 16 + l16;
    rowm[mt] = r < N ? r : N - 1;
  }

  uint4 a_buf[2][2], b_buf[2][4];
  #pragma unroll
  for (int mt = 0; mt < 2; ++mt)
    a_buf[0][mt] = *(const uint4*)(A0 + (size_t)rowm[mt] * 128 + quad * 8);
  {
    const ushort* bp = Bfm + (size_t)(wn * 4 * 256 + lane) * 8;
    #pragma unroll
    for (int nt = 0; nt < 4; ++nt)
      b_buf[0][nt] = *(const uint4*)(bp + nt * 2048);
  }

  f32x4 acc[2][4] = {};

  #pragma unroll
  for (int kt = 0; kt < 8; ++kt) {
    if (kt < 7) {
      int k1 = kt + 1;
      const ushort* bse = (k1 < 4) ? A0 : A1;
      int ko = (k1 & 3) * 32 + quad * 8;
      #pragma unroll
      for (int mt = 0; mt < 2; ++mt)
        a_buf[k1 & 1][mt] = *(const uint4*)(bse + (size_t)rowm[mt] * 128 + ko);
      const ushort* bp = Bfm + ((size_t)(k1 >> 2) * 16384 +
                                (size_t)((wn * 4) * 256 + (k1 & 3) * 64 + lane) * 8);
      #pragma unroll
      for (int nt = 0; nt < 4; ++nt)
        b_buf[k1 & 1][nt] = *(const uint4*)(bp + nt * 2048);
    }
    __builtin_amdgcn_sched_barrier(0);   // loads stay issued ahead of the MFMAs
    #pragma unroll
    for (int mt = 0; mt < 2; ++mt) {
      bf16x8 af = __builtin_bit_cast(bf16x8, a_buf[kt & 1][mt]);
      #pragma unroll
      for (int nt = 0; nt < 4; ++nt)
        acc[mt][nt] = __builtin_amdgcn_mfma_f32_16x16x32_bf16(
            af, __builtin_bit_cast(bf16x8, b_buf[kt & 1][nt]), acc[mt][nt], 0, 0, 0);
    }
  }

  // bias + BN + ReLU in registers
  #pragma unroll
  for (int nt = 0; nt < 4; ++nt) {
    int c = wn * 64 + nt * 16 + l16;
    float sc = gamma[c] * rsqrtf(var[c] + BN_EPS);
    float sh = beta[c] - mean[c] * sc;
    float bi = bias[c];
    #pragma unroll
    for (int mt = 0; mt < 2; ++mt)
      #pragma unroll
      for (int r = 0; r < 4; ++r)
        acc[mt][nt][r] = fmaxf((acc[mt][nt][r] + bi) * sc + sh, 0.f);
  }

  // fence: all waves' A0 reads complete before any wave overwrites those rows
  __syncthreads();

  // per-wave LDS bounce for vectorized residual+store
  float* Cb = Cb_all + wave * (16 * 68);
  #pragma unroll
  for (int mt = 0; mt < 2; ++mt) {
    #pragma unroll
    for (int nt = 0; nt < 4; ++nt)
      #pragma unroll
      for (int r = 0; r < 4; ++r)
        Cb[(quad * 4 + r) * 68 + nt * 16 + l16] = acc[mt][nt][r];
    #pragma unroll
    for (int i = 0; i < 4; ++i) {
      int idx = i * 64 + lane, rowl = idx >> 4, seg = idx & 15;
      int grow = m0 + wm * 32 + mt * 16 + rowl;
      if (grow < N) {
        float4 vv = *(float4*)&Cb[rowl * 68 + seg * 4];
        uint2 rv = *(const uint2*)(residual + (size_t)grow * 128 + wn * 64 + seg * 4);
        vv.x += bf2f_lo(rv.x); vv.y += bf2f_hi(rv.x);
        vv.z += bf2f_lo(rv.y); vv.w += bf2f_hi(rv.y);
        if (F32OUT) {
          *(float4*)((float*)out + (size_t)grow * 128 + wn * 64 + seg * 4) = vv;
        } else {
          uint2 o;
          o.x = pack2(vv.x, vv.y); o.y = pack2(vv.z, vv.w);
          *(uint2*)((ushort*)out + (size_t)grow * 128 + wn * 64 + seg * 4) = o;
          uint u8 = f2e4m3(vv.x) | (f2e4m3(vv.y) << 8) |
                    (f2e4m3(vv.z) << 16) | (f2e4m3(vv.w) << 24);
          *(uint*)(out8 + (size_t)grow * 128 + wn * 64 + seg * 4) = u8;
        }
      }
    }
  }
}

// ---------------- MFMA GEMM (input proj) UNION edge histogram ----------------

__global__ __launch_bounds__(256, 4)
void gemm_in_hist(const float* __restrict__ X, const ushort* __restrict__ Bfm,
                  const float* __restrict__ bias,
                  const float* __restrict__ gamma, const float* __restrict__ beta,
                  const float* __restrict__ mean, const float* __restrict__ var,
                  ushort* __restrict__ out, uchar* __restrict__ out8,
                  const int* __restrict__ dst, int* __restrict__ cnt,
                  int N, int E, int GB) {
  __shared__ float Cb_all[4 * 16 * 68];
  if (blockIdx.x >= GB) {
    int e = (blockIdx.x - GB) * 256 + threadIdx.x;
    if (e < E) atomicAdd(&cnt[dst[e]], 1);
    return;
  }
  int tid = threadIdx.x, wave = tid >> 6, lane = tid & 63;
  int wm = wave >> 1, wn = wave & 1, quad = lane >> 4, l16 = lane & 15;
  int m0 = blockIdx.x * 64;

  int rowm[2];
  #pragma unroll
  for (int mt = 0; mt < 2; ++mt) {
    int r = m0 + wm * 32 + mt * 16 + l16;
    rowm[mt] = r < N ? r : N - 1;
  }

  float4 f_buf[2][2][2];
  uint4 b_buf[2][4];
  #pragma unroll
  for (int mt = 0; mt < 2; ++mt) {
    const float* p = X + (size_t)rowm[mt] * 256 + quad * 8;
    f_buf[0][mt][0] = *(const float4*)p;
    f_buf[0][mt][1] = *(const float4*)(p + 4);
  }
  {
    const ushort* bp = Bfm + (size_t)(wn * 4 * 256 + lane) * 8;
    #pragma unroll
    for (int nt = 0; nt < 4; ++nt)
      b_buf[0][nt] = *(const uint4*)(bp + nt * 2048);
  }

  f32x4 acc[2][4] = {};

  #pragma unroll
  for (int kt = 0; kt < 8; ++kt) {
    if (kt < 7) {
      int k1 = kt + 1;
      int ko = k1 * 32 + quad * 8;
      #pragma unroll
      for (int mt = 0; mt < 2; ++mt) {
        const float* p = X + (size_t)rowm[mt] * 256 + ko;
        f_buf[k1 & 1][mt][0] = *(const float4*)p;
        f_buf[k1 & 1][mt][1] = *(const float4*)(p + 4);
      }
      const ushort* bp = Bfm + ((size_t)(k1 >> 2) * 16384 +
                                (size_t)((wn * 4) * 256 + (k1 & 3) * 64 + lane) * 8);
      #pragma unroll
      for (int nt = 0; nt < 4; ++nt)
        b_buf[k1 & 1][nt] = *(const uint4*)(bp + nt * 2048);
    }
    __builtin_amdgcn_sched_barrier(0);
    #pragma unroll
    for (int mt = 0; mt < 2; ++mt) {
      float4 lo = f_buf[kt & 1][mt][0], hi = f_buf[kt & 1][mt][1];
      uint4 av;
      av.x = pack2(lo.x, lo.y); av.y = pack2(lo.z, lo.w);
      av.z = pack2(hi.x, hi.y); av.w = pack2(hi.z, hi.w);
      bf16x8 af = __builtin_bit_cast(bf16x8, av);
      #pragma unroll
      for (int nt = 0; nt < 4; ++nt)
        acc[mt][nt] = __builtin_amdgcn_mfma_f32_16x16x32_bf16(
            af, __builtin_bit_cast(bf16x8, b_buf[kt & 1][nt]), acc[mt][nt], 0, 0, 0);
    }
  }

  #pragma unroll
  for (int nt = 0; nt < 4; ++nt) {
    int c = wn * 64 + nt * 16 + l16;
    float sc = gamma[c] * rsqrtf(var[c] + BN_EPS);
    float sh = beta[c] - mean[c] * sc;
    float bi = bias[c];
    #pragma unroll
    for (int mt = 0; mt < 2; ++mt)
      #pragma unroll
      for (int r = 0; r < 4; ++r)
        acc[mt][nt][r] = fmaxf((acc[mt][nt][r] + bi) * sc + sh, 0.f);
  }

  float* Cb = Cb_all + wave * (16 * 68);
  #pragma unroll
  for (int mt = 0; mt < 2; ++mt) {
    #pragma unroll
    for (int nt = 0; nt < 4; ++nt)
      #pragma unroll
      for (int r = 0; r < 4; ++r)
        Cb[(quad * 4 + r) * 68 + nt * 16 + l16] = acc[mt][nt][r];
    #pragma unroll
    for (int i = 0; i < 4; ++i) {
      int idx = i * 64 + lane, rowl = idx >> 4, seg = idx & 15;
      int grow = m0 + wm * 32 + mt * 16 + rowl;
      if (grow < N) {
        float4 vv = *(float4*)&Cb[rowl * 68 + seg * 4];
        uint2 o;
        o.x = pack2(vv.x, vv.y); o.y = pack2(vv.z, vv.w);
        *(uint2*)(out + (size_t)grow * 128 + wn * 64 + seg * 4) = o;
        uint u8 = f2e4m3(vv.x) | (f2e4m3(vv.y) << 8) |
                  (f2e4m3(vv.z) << 16) | (f2e4m3(vv.w) << 24);
        *(uint*)(out8 + (size_t)grow * 128 + wn * 64 + seg * 4) = u8;
      }
    }
  }
}

// ---------------- launch ----------------

extern "C" void kernel_launch(void* const* d_in, const int* in_sizes, int n_in,
                              void* d_out, int out_size, void* d_ws, size_t ws_size,
                              hipStream_t stream) {
  const float* x      = (const float*)d_in[0];
  const int*   eidx   = (const int*)d_in[1];
  const float* W_in   = (const float*)d_in[2];
  const float* b_in   = (const float*)d_in[3];
  const float* bng_in = (const float*)d_in[4];
  const float* bnb_in = (const float*)d_in[5];
  const float* bnm_in = (const float*)d_in[6];
  const float* bnv_in = (const float*)d_in[7];
  const float* Wl     = (const float*)d_in[8];
  const float* bl     = (const float*)d_in[9];
  const float* Wr     = (const float*)d_in[10];
  const float* bng    = (const float*)d_in[11];
  const float* bnb    = (const float*)d_in[12];
  const float* bnm    = (const float*)d_in[13];
  const float* bnv    = (const float*)d_in[14];

  const int N = in_sizes[0] / 256;
  const int E = in_sizes[1] / 2;
  const int NB = (N + 255) / 256;
  const int* src = eidx;
  const int* dst = eidx + E;

  char* ws = (char*)d_ws;
  size_t off = 0;
  auto alloc = [&](size_t bytes) {
    void* p = ws + off;
    off = (off + bytes + 255) & ~(size_t)255;
    return p;
  };
  // Total footprint ~68 MB — BELOW the round-8-proven ~81 MB (rounds 9/10
  // grew to 94-106 MB and the container died both times: suspected overflow).
  int* zreg     = (int*)alloc((size_t)(2 * N + 1) * 4);   // cnt(deg) | cur | cursor
  int* cnt      = zreg;
  int* cur      = zreg + N;
  int* cursor   = zreg + 2 * N;
  int* rowbeg   = (int*)alloc((size_t)N * 4);
  int* col      = (int*)alloc((size_t)E * 4);
  ushort* Bfm   = (ushort*)alloc(4 * 32768 * 2);   // split-K frag-major: [in, l0, l1, l2]
  ushort* bufA  = (ushort*)alloc((size_t)N * 128 * 2);
  ushort* bufB  = (ushort*)alloc((size_t)N * 128 * 2);
  uchar* h8     = (uchar*)alloc((size_t)N * 128);   // fp8 e4m3 shadow (agg path)
  (void)ws_size; (void)n_in; (void)out_size;

  const int EB = (E + 255) / 256;
  const int GB = (N + 63) / 64;

  // counters zero + weight prep (Bfm MUST be ready before gemm_in_hist)
  hipMemsetAsync(zreg, 0, (size_t)(2 * N + 1) * 4, stream);
  prep_weights_fm<<<64, 256, 0, stream>>>(W_in, Wl, Wr, Bfm);

  // input projection UNION edge histogram (independent outputs)
  gemm_in_hist<<<GB + EB, 256, 0, stream>>>(x, Bfm, b_in, bng_in, bnb_in, bnm_in, bnv_in,
                                            bufA, h8, dst, cnt, N, E, GB);

  // CSR range reserve (bump allocation), then fill
  reserve_kernel<<<NB, 256, 0, stream>>>(cnt, rowbeg, cursor, N);
  fill_kernel<<<EB, 256, 0, stream>>>(src, dst, rowbeg, cur, col, E);

  // 3 SAGE layers with 2-buffer rotation: h_l lives in one buffer; agg is
  // written into the OTHER buffer and the GEMM overwrites it in place with
  // h_{l+1} (out aliases A0; per-block row ownership + in-kernel barrier).
  // h8 is rewritten by each GEMM after the agg that read it (stream-serial).
  for (int l = 0; l < 3; ++l) {
    ushort* h_in   = (l & 1) ? bufB : bufA;
    ushort* aggbuf = (l & 1) ? bufA : bufB;
    agg_kernel<<<(N + 15) / 16, 256, 0, stream>>>(rowbeg, cnt, col, h8, aggbuf, N);
    const ushort* BfmL = Bfm + (size_t)(l + 1) * 32768;
    const float* biasL = bl + l * 128;
    if (l < 2) {
      gemm_layer<false><<<GB, 256, 0, stream>>>(aggbuf, h_in, BfmL, biasL,
          bng + l * 128, bnb + l * 128, bnm + l * 128, bnv + l * 128,
          h_in, (void*)aggbuf, h8, N);
    } else {
      gemm_layer<true><<<GB, 256, 0, stream>>>(aggbuf, h_in, BfmL, biasL,
          bng + l * 128, bnb + l * 128, bnm + l * 128, bnv + l * 128,
          h_in, d_out, nullptr, N);
    }
  }
}

// Round 12
// 422.824 us; speedup vs baseline: 2.9966x; 1.0071x over previous
//
#include <hip/hip_runtime.h>

#define BN_EPS 1e-5f

typedef __bf16 bf16x8 __attribute__((ext_vector_type(8)));
typedef float f32x4 __attribute__((ext_vector_type(4)));
typedef unsigned int uint;
typedef unsigned short ushort;
typedef unsigned char uchar;

__device__ __forceinline__ ushort f2bf(float f) {
  union { float f; uint u; } v; v.f = f;
  uint r = v.u + 0x7FFF + ((v.u >> 16) & 1);   // RNE
  return (ushort)(r >> 16);
}
__device__ __forceinline__ float bf2f_lo(uint u) {
  union { uint i; float f; } v; v.i = u << 16; return v.f;
}
__device__ __forceinline__ float bf2f_hi(uint u) {
  union { uint i; float f; } v; v.i = u & 0xffff0000u; return v.f;
}
__device__ __forceinline__ uint pack2(float a, float b) {
  return (uint)f2bf(a) | ((uint)f2bf(b) << 16);
}

// ---- fp8 e4m3 (non-negative h only; h >= 0 holds inductively: ReLU + residual) ----
__device__ __forceinline__ uint f2e4m3(float f) {
  union { float f; uint u; } v; v.f = f * 0x1p-120f;
  uint r = v.u + 0x7FFFF + ((v.u >> 20) & 1);
  uint u8 = r >> 20;
  return u8 > 0x7Eu ? 0x7Eu : u8;
}
__device__ __forceinline__ float e4m32f(uint u8) {
  union { uint u; float f; } v; v.u = (u8 & 0x7Fu) << 20;
  return v.f * 0x1p120f;
}

// ---------------- zero counters + weight prep (one kernel) ----------------
// Blocks < NB2 zero cnt|cur|cursor; blocks >= NB2 build split-K frag-major
// bf16 weights. Completes fully before gemm_in_hist (stream-serial), so both
// the zeroed cnt and Bfm are ready — ordering preserved (round-6 lesson).

__global__ void zero_prep_kernel(int* __restrict__ zreg, int NZ,
                                 const float* __restrict__ W_in, const float* __restrict__ Wl,
                                 const float* __restrict__ Wr, ushort* __restrict__ Bfm,
                                 int NB2) {
  int b = blockIdx.x;
  if (b < NB2) {
    int i = b * 256 + threadIdx.x;
    if (i < NZ) zreg[i] = 0;
    return;
  }
  int p = (b - NB2) * 256 + threadIdx.x;
  int mat = p >> 12;
  int rem = p & 4095;
  int half = rem >> 11;
  int rem2 = rem & 2047;
  int nt = rem2 >> 8, kt2 = (rem2 >> 6) & 3, lane = rem2 & 63;
  int n = nt * 16 + (lane & 15);
  int k0 = (half * 4 + kt2) * 32 + (lane >> 4) * 8;
  ushort tmp[8];
  #pragma unroll
  for (int j = 0; j < 8; ++j) {
    int k = k0 + j;
    float v;
    if (mat == 0) v = W_in[k * 128 + n];
    else {
      int l = mat - 1;
      v = (k < 128) ? Wl[l * 16384 + k * 128 + n] : Wr[l * 16384 + (k - 128) * 128 + n];
    }
    tmp[j] = f2bf(v);
  }
  *(uint4*)&Bfm[(size_t)p * 8] = *(const uint4*)tmp;
}

// ---------------- CSR build (bump allocation) ----------------

__global__ void reserve_kernel(const int* __restrict__ cnt, int* __restrict__ rowbeg,
                               int* __restrict__ cursor, int N) {
  int tid = threadIdx.x;
  int i = blockIdx.x * 256 + tid;
  int v = (i < N) ? cnt[i] : 0;
  int lane = tid & 63;
  int x = v;
  #pragma unroll
  for (int off = 1; off < 64; off <<= 1) {
    int y = __shfl_up(x, off, 64);
    if (lane >= off) x += y;
  }
  int ret = 0;
  if (lane == 63) ret = atomicAdd(cursor, x);
  int base = __shfl(ret, 63);
  if (i < N) rowbeg[i] = base + x - v;
}

__global__ void fill_kernel(const int* __restrict__ src, const int* __restrict__ dst,
                            const int* __restrict__ rowbeg, int* __restrict__ cur,
                            int* __restrict__ col, int E) {
  int e = blockIdx.x * 256 + threadIdx.x;
  if (e < E) {
    int d = dst[e];
    int p = rowbeg[d] + atomicAdd(&cur[d], 1);
    col[p] = src[e];
  }
}

// ---------------- mean aggregation: fp8 gather, quarter-wave per node -----

__global__ void agg_kernel(const int* __restrict__ rowbeg, const int* __restrict__ deg,
                           const int* __restrict__ col,
                           const uchar* __restrict__ h8, ushort* __restrict__ agg, int N) {
  int node = blockIdx.x * 16 + (threadIdx.x >> 4);
  if (node >= N) return;
  int lane = threadIdx.x & 15;
  const uchar* hp = h8 + lane * 8;
  int beg = rowbeg[node];
  int d = deg[node];
  float di = 1.0f / (float)(d > 0 ? d : 1);
  int end = beg + d;
  float a0 = 0.f, a1 = 0.f, a2 = 0.f, a3 = 0.f;
  float a4 = 0.f, a5 = 0.f, a6 = 0.f, a7 = 0.f;
  #pragma unroll 1
  for (int e = beg; e < end; e += 8) {
    int cc[8];
    #pragma unroll
    for (int j = 0; j < 8; ++j) {
      int idx = e + j;
      cc[j] = col[idx < end ? idx : e];
    }
    uint2 v[8];
    #pragma unroll
    for (int j = 0; j < 8; ++j)
      v[j] = *(const uint2*)(hp + (size_t)cc[j] * 128);
    #pragma unroll
    for (int j = 1; j < 8; ++j)
      if (e + j >= end) { v[j].x = 0u; v[j].y = 0u; }
    #pragma unroll
    for (int j = 0; j < 8; ++j) {
      a0 += e4m32f(v[j].x);        a1 += e4m32f(v[j].x >> 8);
      a2 += e4m32f(v[j].x >> 16);  a3 += e4m32f(v[j].x >> 24);
      a4 += e4m32f(v[j].y);        a5 += e4m32f(v[j].y >> 8);
      a6 += e4m32f(v[j].y >> 16);  a7 += e4m32f(v[j].y >> 24);
    }
  }
  uint4 o;
  o.x = pack2(a0 * di, a1 * di);
  o.y = pack2(a2 * di, a3 * di);
  o.z = pack2(a4 * di, a5 * di);
  o.w = pack2(a6 * di, a7 * di);
  *(uint4*)(agg + (size_t)node * 128 + lane * 8) = o;
}

// ---------------- MFMA GEMM (layers): BM=64, in-place over A0, depth-2 A ------
// out ALIASES A0 (in-place; __syncthreads() fences reads before stores).
// A-loads (agg/h: HBM/L3, ~900cy) run depth-2 (3-slot a_buf, static index
// under full unroll) so two loads are in flight — halves the serialized
// latency chain that made the k-loop stall-bound. B stays depth-1 (L2-hot).

template<bool F32OUT>
__global__ __launch_bounds__(256, 4)
void gemm_layer(const ushort* A0, const ushort* __restrict__ A1,
                const ushort* __restrict__ Bfm, const float* __restrict__ bias,
                const float* __restrict__ gamma, const float* __restrict__ beta,
                const float* __restrict__ mean, const float* __restrict__ var,
                const ushort* residual, void* out,
                uchar* __restrict__ out8, int N) {
  __shared__ float Cb_all[4 * 16 * 68];
  int tid = threadIdx.x, wave = tid >> 6, lane = tid & 63;
  int wm = wave >> 1, wn = wave & 1, quad = lane >> 4, l16 = lane & 15;
  int m0 = blockIdx.x * 64;

  int rowm[2];
  #pragma unroll
  for (int mt = 0; mt < 2; ++mt) {
    int r = m0 + wm * 32 + mt * 16 + l16;
    rowm[mt] = r < N ? r : N - 1;
  }

  uint4 a_buf[3][2], b_buf[2][4];
  #pragma unroll
  for (int mt = 0; mt < 2; ++mt) {
    a_buf[0][mt] = *(const uint4*)(A0 + (size_t)rowm[mt] * 128 + quad * 8);
    a_buf[1][mt] = *(const uint4*)(A0 + (size_t)rowm[mt] * 128 + 32 + quad * 8);
  }
  {
    const ushort* bp = Bfm + (size_t)(wn * 4 * 256 + lane) * 8;
    #pragma unroll
    for (int nt = 0; nt < 4; ++nt)
      b_buf[0][nt] = *(const uint4*)(bp + nt * 2048);
  }

  f32x4 acc[2][4] = {};

  #pragma unroll
  for (int kt = 0; kt < 8; ++kt) {
    if (kt < 6) {
      int k2 = kt + 2;
      const ushort* bse = (k2 < 4) ? A0 : A1;
      int ko = (k2 & 3) * 32 + quad * 8;
      #pragma unroll
      for (int mt = 0; mt < 2; ++mt)
        a_buf[k2 % 3][mt] = *(const uint4*)(bse + (size_t)rowm[mt] * 128 + ko);
    }
    if (kt < 7) {
      int k1 = kt + 1;
      const ushort* bp = Bfm + ((size_t)(k1 >> 2) * 16384 +
                                (size_t)((wn * 4) * 256 + (k1 & 3) * 64 + lane) * 8);
      #pragma unroll
      for (int nt = 0; nt < 4; ++nt)
        b_buf[k1 & 1][nt] = *(const uint4*)(bp + nt * 2048);
    }
    __builtin_amdgcn_sched_barrier(0);   // loads stay issued ahead of the MFMAs
    #pragma unroll
    for (int mt = 0; mt < 2; ++mt) {
      bf16x8 af = __builtin_bit_cast(bf16x8, a_buf[kt % 3][mt]);
      #pragma unroll
      for (int nt = 0; nt < 4; ++nt)
        acc[mt][nt] = __builtin_amdgcn_mfma_f32_16x16x32_bf16(
            af, __builtin_bit_cast(bf16x8, b_buf[kt & 1][nt]), acc[mt][nt], 0, 0, 0);
    }
  }

  // bias + BN + ReLU in registers
  #pragma unroll
  for (int nt = 0; nt < 4; ++nt) {
    int c = wn * 64 + nt * 16 + l16;
    float sc = gamma[c] * rsqrtf(var[c] + BN_EPS);
    float sh = beta[c] - mean[c] * sc;
    float bi = bias[c];
    #pragma unroll
    for (int mt = 0; mt < 2; ++mt)
      #pragma unroll
      for (int r = 0; r < 4; ++r)
        acc[mt][nt][r] = fmaxf((acc[mt][nt][r] + bi) * sc + sh, 0.f);
  }

  // fence: all waves' A0 reads complete before any wave overwrites those rows
  __syncthreads();

  // per-wave LDS bounce for vectorized residual+store
  float* Cb = Cb_all + wave * (16 * 68);
  #pragma unroll
  for (int mt = 0; mt < 2; ++mt) {
    #pragma unroll
    for (int nt = 0; nt < 4; ++nt)
      #pragma unroll
      for (int r = 0; r < 4; ++r)
        Cb[(quad * 4 + r) * 68 + nt * 16 + l16] = acc[mt][nt][r];
    #pragma unroll
    for (int i = 0; i < 4; ++i) {
      int idx = i * 64 + lane, rowl = idx >> 4, seg = idx & 15;
      int grow = m0 + wm * 32 + mt * 16 + rowl;
      if (grow < N) {
        float4 vv = *(float4*)&Cb[rowl * 68 + seg * 4];
        uint2 rv = *(const uint2*)(residual + (size_t)grow * 128 + wn * 64 + seg * 4);
        vv.x += bf2f_lo(rv.x); vv.y += bf2f_hi(rv.x);
        vv.z += bf2f_lo(rv.y); vv.w += bf2f_hi(rv.y);
        if (F32OUT) {
          *(float4*)((float*)out + (size_t)grow * 128 + wn * 64 + seg * 4) = vv;
        } else {
          uint2 o;
          o.x = pack2(vv.x, vv.y); o.y = pack2(vv.z, vv.w);
          *(uint2*)((ushort*)out + (size_t)grow * 128 + wn * 64 + seg * 4) = o;
          uint u8 = f2e4m3(vv.x) | (f2e4m3(vv.y) << 8) |
                    (f2e4m3(vv.z) << 16) | (f2e4m3(vv.w) << 24);
          *(uint*)(out8 + (size_t)grow * 128 + wn * 64 + seg * 4) = u8;
        }
      }
    }
  }
}

// ---------------- MFMA GEMM (input proj, depth-2 X) UNION edge histogram ------
// X reads (fp32, HBM-cold, ~900cy) run depth-2: 3-slot f_buf, static index
// under full unroll, two loads in flight. B depth-1.

__global__ __launch_bounds__(256, 4)
void gemm_in_hist(const float* __restrict__ X, const ushort* __restrict__ Bfm,
                  const float* __restrict__ bias,
                  const float* __restrict__ gamma, const float* __restrict__ beta,
                  const float* __restrict__ mean, const float* __restrict__ var,
                  ushort* __restrict__ out, uchar* __restrict__ out8,
                  const int* __restrict__ dst, int* __restrict__ cnt,
                  int N, int E, int GB) {
  __shared__ float Cb_all[4 * 16 * 68];
  if (blockIdx.x >= GB) {
    int e = (blockIdx.x - GB) * 256 + threadIdx.x;
    if (e < E) atomicAdd(&cnt[dst[e]], 1);
    return;
  }
  int tid = threadIdx.x, wave = tid >> 6, lane = tid & 63;
  int wm = wave >> 1, wn = wave & 1, quad = lane >> 4, l16 = lane & 15;
  int m0 = blockIdx.x * 64;

  int rowm[2];
  #pragma unroll
  for (int mt = 0; mt < 2; ++mt) {
    int r = m0 + wm * 32 + mt * 16 + l16;
    rowm[mt] = r < N ? r : N - 1;
  }

  float4 f_buf[3][2][2];
  uint4 b_buf[2][4];
  #pragma unroll
  for (int mt = 0; mt < 2; ++mt) {
    const float* p0 = X + (size_t)rowm[mt] * 256 + quad * 8;
    f_buf[0][mt][0] = *(const float4*)p0;
    f_buf[0][mt][1] = *(const float4*)(p0 + 4);
    const float* p1 = X + (size_t)rowm[mt] * 256 + 32 + quad * 8;
    f_buf[1][mt][0] = *(const float4*)p1;
    f_buf[1][mt][1] = *(const float4*)(p1 + 4);
  }
  {
    const ushort* bp = Bfm + (size_t)(wn * 4 * 256 + lane) * 8;
    #pragma unroll
    for (int nt = 0; nt < 4; ++nt)
      b_buf[0][nt] = *(const uint4*)(bp + nt * 2048);
  }

  f32x4 acc[2][4] = {};

  #pragma unroll
  for (int kt = 0; kt < 8; ++kt) {
    if (kt < 6) {
      int k2 = kt + 2;
      int ko = k2 * 32 + quad * 8;
      #pragma unroll
      for (int mt = 0; mt < 2; ++mt) {
        const float* p = X + (size_t)rowm[mt] * 256 + ko;
        f_buf[k2 % 3][mt][0] = *(const float4*)p;
        f_buf[k2 % 3][mt][1] = *(const float4*)(p + 4);
      }
    }
    if (kt < 7) {
      int k1 = kt + 1;
      const ushort* bp = Bfm + ((size_t)(k1 >> 2) * 16384 +
                                (size_t)((wn * 4) * 256 + (k1 & 3) * 64 + lane) * 8);
      #pragma unroll
      for (int nt = 0; nt < 4; ++nt)
        b_buf[k1 & 1][nt] = *(const uint4*)(bp + nt * 2048);
    }
    __builtin_amdgcn_sched_barrier(0);
    #pragma unroll
    for (int mt = 0; mt < 2; ++mt) {
      float4 lo = f_buf[kt % 3][mt][0], hi = f_buf[kt % 3][mt][1];
      uint4 av;
      av.x = pack2(lo.x, lo.y); av.y = pack2(lo.z, lo.w);
      av.z = pack2(hi.x, hi.y); av.w = pack2(hi.z, hi.w);
      bf16x8 af = __builtin_bit_cast(bf16x8, av);
      #pragma unroll
      for (int nt = 0; nt < 4; ++nt)
        acc[mt][nt] = __builtin_amdgcn_mfma_f32_16x16x32_bf16(
            af, __builtin_bit_cast(bf16x8, b_buf[kt & 1][nt]), acc[mt][nt], 0, 0, 0);
    }
  }

  #pragma unroll
  for (int nt = 0; nt < 4; ++nt) {
    int c = wn * 64 + nt * 16 + l16;
    float sc = gamma[c] * rsqrtf(var[c] + BN_EPS);
    float sh = beta[c] - mean[c] * sc;
    float bi = bias[c];
    #pragma unroll
    for (int mt = 0; mt < 2; ++mt)
      #pragma unroll
      for (int r = 0; r < 4; ++r)
        acc[mt][nt][r] = fmaxf((acc[mt][nt][r] + bi) * sc + sh, 0.f);
  }

  float* Cb = Cb_all + wave * (16 * 68);
  #pragma unroll
  for (int mt = 0; mt < 2; ++mt) {
    #pragma unroll
    for (int nt = 0; nt < 4; ++nt)
      #pragma unroll
      for (int r = 0; r < 4; ++r)
        Cb[(quad * 4 + r) * 68 + nt * 16 + l16] = acc[mt][nt][r];
    #pragma unroll
    for (int i = 0; i < 4; ++i) {
      int idx = i * 64 + lane, rowl = idx >> 4, seg = idx & 15;
      int grow = m0 + wm * 32 + mt * 16 + rowl;
      if (grow < N) {
        float4 vv = *(float4*)&Cb[rowl * 68 + seg * 4];
        uint2 o;
        o.x = pack2(vv.x, vv.y); o.y = pack2(vv.z, vv.w);
        *(uint2*)(out + (size_t)grow * 128 + wn * 64 + seg * 4) = o;
        uint u8 = f2e4m3(vv.x) | (f2e4m3(vv.y) << 8) |
                  (f2e4m3(vv.z) << 16) | (f2e4m3(vv.w) << 24);
        *(uint*)(out8 + (size_t)grow * 128 + wn * 64 + seg * 4) = u8;
      }
    }
  }
}

// ---------------- launch ----------------

extern "C" void kernel_launch(void* const* d_in, const int* in_sizes, int n_in,
                              void* d_out, int out_size, void* d_ws, size_t ws_size,
                              hipStream_t stream) {
  const float* x      = (const float*)d_in[0];
  const int*   eidx   = (const int*)d_in[1];
  const float* W_in   = (const float*)d_in[2];
  const float* b_in   = (const float*)d_in[3];
  const float* bng_in = (const float*)d_in[4];
  const float* bnb_in = (const float*)d_in[5];
  const float* bnm_in = (const float*)d_in[6];
  const float* bnv_in = (const float*)d_in[7];
  const float* Wl     = (const float*)d_in[8];
  const float* bl     = (const float*)d_in[9];
  const float* Wr     = (const float*)d_in[10];
  const float* bng    = (const float*)d_in[11];
  const float* bnb    = (const float*)d_in[12];
  const float* bnm    = (const float*)d_in[13];
  const float* bnv    = (const float*)d_in[14];

  const int N = in_sizes[0] / 256;
  const int E = in_sizes[1] / 2;
  const int NB = (N + 255) / 256;
  const int* src = eidx;
  const int* dst = eidx + E;

  char* ws = (char*)d_ws;
  size_t off = 0;
  auto alloc = [&](size_t bytes) {
    void* p = ws + off;
    off = (off + bytes + 255) & ~(size_t)255;
    return p;
  };
  // Total footprint ~68 MB (round-11-proven; rounds 9/10 at 94-106 MB died).
  int* zreg     = (int*)alloc((size_t)(2 * N + 1) * 4);   // cnt(deg) | cur | cursor
  int* cnt      = zreg;
  int* cur      = zreg + N;
  int* cursor   = zreg + 2 * N;
  int* rowbeg   = (int*)alloc((size_t)N * 4);
  int* col      = (int*)alloc((size_t)E * 4);
  ushort* Bfm   = (ushort*)alloc(4 * 32768 * 2);   // split-K frag-major: [in, l0, l1, l2]
  ushort* bufA  = (ushort*)alloc((size_t)N * 128 * 2);
  ushort* bufB  = (ushort*)alloc((size_t)N * 128 * 2);
  uchar* h8     = (uchar*)alloc((size_t)N * 128);   // fp8 e4m3 shadow (agg path)
  (void)ws_size; (void)n_in; (void)out_size;

  const int EB = (E + 255) / 256;
  const int GB = (N + 63) / 64;
  const int NZ = 2 * N + 1;
  const int NB2 = (NZ + 255) / 256;

  // zero counters + weight prep in ONE kernel (completes before gemm_in_hist)
  zero_prep_kernel<<<NB2 + 64, 256, 0, stream>>>(zreg, NZ, W_in, Wl, Wr, Bfm, NB2);

  // input projection UNION edge histogram (independent outputs)
  gemm_in_hist<<<GB + EB, 256, 0, stream>>>(x, Bfm, b_in, bng_in, bnb_in, bnm_in, bnv_in,
                                            bufA, h8, dst, cnt, N, E, GB);

  // CSR range reserve (bump allocation), then fill
  reserve_kernel<<<NB, 256, 0, stream>>>(cnt, rowbeg, cursor, N);
  fill_kernel<<<EB, 256, 0, stream>>>(src, dst, rowbeg, cur, col, E);

  // 3 SAGE layers, 2-buffer rotation with in-place GEMM over the agg buffer
  for (int l = 0; l < 3; ++l) {
    ushort* h_in   = (l & 1) ? bufB : bufA;
    ushort* aggbuf = (l & 1) ? bufA : bufB;
    agg_kernel<<<(N + 15) / 16, 256, 0, stream>>>(rowbeg, cnt, col, h8, aggbuf, N);
    const ushort* BfmL = Bfm + (size_t)(l + 1) * 32768;
    const float* biasL = bl + l * 128;
    if (l < 2) {
      gemm_layer<false><<<GB, 256, 0, stream>>>(aggbuf, h_in, BfmL, biasL,
          bng + l * 128, bnb + l * 128, bnm + l * 128, bnv + l * 128,
          h_in, (void*)aggbuf, h8, N);
    } else {
      gemm_layer<true><<<GB, 256, 0, stream>>>(aggbuf, h_in, BfmL, biasL,
          bng + l * 128, bnb + l * 128, bnm + l * 128, bnv + l * 128,
          h_in, d_out, nullptr, N);
    }
  }
}